// Round 7
// baseline (303.058 us; speedup 1.0000x reference)
//
#include <hip/hip_runtime.h>
#include <hip/hip_bf16.h>
#include <math.h>

// Problem constants
#define BB 4
#define NN 2048
#define DIM 384
#define HEADS 8
#define HD 48
#define MLPH 1536
#define ROWS (BB*NN)          // 8192
#define SZ ((size_t)ROWS*DIM) // 3145728 elems per (B,N,DIM) buffer

typedef float floatx4 __attribute__((ext_vector_type(4)));
typedef short shortx8 __attribute__((ext_vector_type(8)));

__device__ __forceinline__ float gelu_exact(float x) {
    return 0.5f * x * (1.0f + erff(x * 0.70710678118654752f));
}

__device__ __forceinline__ short f2bf(float f) {
    __hip_bfloat16 h = __float2bfloat16(f);
    return *reinterpret_cast<short*>(&h);
}

// ---------------- LayerNorm: 4 rows/block (one wave each), fp32 -> bf16 ----------------
__global__ __launch_bounds__(256) void ln_bf16_kernel(const float* __restrict__ x,
                                                      const float* __restrict__ g,
                                                      const float* __restrict__ be,
                                                      short* __restrict__ out) {
    int row = blockIdx.x * 4 + (threadIdx.x >> 6);
    int lane = threadIdx.x & 63;
    const float* xp = x + (size_t)row * DIM;
    float v[6];
    float sum = 0.f, sumsq = 0.f;
#pragma unroll
    for (int j = 0; j < 6; j++) {
        float val = xp[lane + j * 64];
        v[j] = val; sum += val; sumsq += val * val;
    }
#pragma unroll
    for (int off = 1; off < 64; off <<= 1) {
        sum += __shfl_xor(sum, off, 64);
        sumsq += __shfl_xor(sumsq, off, 64);
    }
    float mean = sum * (1.f / DIM);
    float var = sumsq * (1.f / DIM) - mean * mean;
    float rstd = rsqrtf(var + 1e-5f);
    short* op = out + (size_t)row * DIM;
#pragma unroll
    for (int j = 0; j < 6; j++) {
        int c = lane + j * 64;
        op[c] = f2bf((v[j] - mean) * rstd * g[c] + be[c]);
    }
}

// ---------------- positional MLP: 4 points/block, pw2 staged in LDS ----------------
__global__ __launch_bounds__(256) void pe_kernel(const float* __restrict__ pos,
                                                 const float* __restrict__ pw1,
                                                 const float* __restrict__ pb1,
                                                 const float* __restrict__ pw2,
                                                 const float* __restrict__ pb2,
                                                 float* __restrict__ pe) {
    __shared__ float pw2s[HD * HD];
    __shared__ float hsh[4][HD];
    int t = threadIdx.x;
    int w = t >> 6, lane = t & 63;
    int p = blockIdx.x * 4 + w;
    for (int i = t; i < HD * HD; i += 256) pw2s[i] = pw2[i];
    float px = pos[(size_t)p * 3 + 0];
    float py = pos[(size_t)p * 3 + 1];
    float pz = pos[(size_t)p * 3 + 2];
    __syncthreads();
    if (lane < HD) {
        float hv = px * pw1[0 * HD + lane] + py * pw1[1 * HD + lane] + pz * pw1[2 * HD + lane] + pb1[lane];
        hsh[w][lane] = gelu_exact(hv);
    }
    // same-wave LDS write->read: compiler inserts lgkmcnt wait
    if (lane < HD) {
        float o = pb2[lane];
#pragma unroll 8
        for (int i = 0; i < HD; i++) o += hsh[w][i] * pw2s[i * HD + lane];
        pe[(size_t)p * HD + lane] = o;
    }
}

// ---------------- fused weight prep: all transposes (fp32 [K][N] -> bf16 [N][K]) + bias ----
__global__ __launch_bounds__(256) void prep_kernel(const float* __restrict__ Wq,
                                                   const float* __restrict__ Wk,
                                                   const float* __restrict__ Wv,
                                                   const float* __restrict__ Wo,
                                                   const float* __restrict__ mw1,
                                                   const float* __restrict__ mw2,
                                                   const float* __restrict__ bq,
                                                   const float* __restrict__ bk,
                                                   const float* __restrict__ bv,
                                                   short* __restrict__ Wqkv_t,
                                                   short* __restrict__ Wo_t,
                                                   short* __restrict__ mw1_t,
                                                   short* __restrict__ mw2_t,
                                                   float* __restrict__ bqkv) {
    __shared__ float tile[32][33];
    int id = blockIdx.x;
    if (id >= 1728) {  // bias concat
        for (int i = threadIdx.x; i < 3 * DIM; i += 256)
            bqkv[i] = i < DIM ? bq[i] : (i < 2 * DIM ? bk[i - DIM] : bv[i - 2 * DIM]);
        return;
    }
    const float* src; short* dst; int K, N, tid;
    if (id < 144)       { src = Wq;  dst = Wqkv_t;               K = 384;  N = 384;  tid = id; }
    else if (id < 288)  { src = Wk;  dst = Wqkv_t + 147456;      K = 384;  N = 384;  tid = id - 144; }
    else if (id < 432)  { src = Wv;  dst = Wqkv_t + 294912;      K = 384;  N = 384;  tid = id - 288; }
    else if (id < 576)  { src = Wo;  dst = Wo_t;                 K = 384;  N = 384;  tid = id - 432; }
    else if (id < 1152) { src = mw1; dst = mw1_t;                K = 384;  N = 1536; tid = id - 576; }
    else                { src = mw2; dst = mw2_t;                K = 1536; N = 384;  tid = id - 1152; }
    int ntx = N / 32;
    int n0 = (tid % ntx) * 32, k0 = (tid / ntx) * 32;
    int c = threadIdx.x & 31, r4 = threadIdx.x >> 5;
#pragma unroll
    for (int i = 0; i < 4; i++) {
        int r = r4 + i * 8;
        tile[r][c] = src[(size_t)(k0 + r) * N + n0 + c];
    }
    __syncthreads();
#pragma unroll
    for (int i = 0; i < 4; i++) {
        int r = r4 + i * 8;
        dst[(size_t)(n0 + r) * K + k0 + c] = f2bf(tile[c][r]);
    }
}

// ---------------- bf16 MFMA GEMM v3: C[M,N] = A[M,K] @ Bt[N,K]^T + bias ----------------
// 128x128 tile, BK=64, 4 waves 2x2. XOR-8 swizzle + 1-tile register prefetch.
// Pure-DS two-barrier staging (round-3 lesson).
// MODE 0: QKV fused -> q/k row-major bf16 (pe added to k), V^T permuted:
//         key_new = 4*(key%16) + key/16 within each 64-key tile (matches attention).
// MODE 1: exact gelu -> bf16 (MLP1)
// MODE 2: of = res + (mask ? v : 0)  fp32 (Wo + residual)
// MODE 3: of = mask ? (res + v) : 0  fp32 (MLP2 + residual + mask)
template <int MODE, int TN>
__global__ __launch_bounds__(256) void gemm3_kernel(const short* __restrict__ A,
                                                    const short* __restrict__ Bt,
                                                    const float* __restrict__ bias,
                                                    const float* __restrict__ pe,
                                                    const float* __restrict__ res,
                                                    const int* __restrict__ mask,
                                                    float* __restrict__ of,
                                                    short* __restrict__ o0,
                                                    short* __restrict__ o1,
                                                    short* __restrict__ o2,
                                                    int M, int N, int K) {
    constexpr int NI = TN / 32;
    __shared__ short As[128 * 64];
    __shared__ short Bs[TN * 64];
    const int t = threadIdx.x, lane = t & 63, w = t >> 6;
    const int l16 = lane & 15, quad = lane >> 4;
    const int m0 = blockIdx.y * 128, n0 = blockIdx.x * TN;
    const int wm = (w & 1) * 64, wn = (w >> 1) * (TN / 2);

    const int rr = t >> 3, gc = t & 7, cshort = gc * 8;
    const short* gA[4]; int ldsoA[4];
    const short* gB[NI]; int ldsoB[NI];
#pragma unroll
    for (int qc = 0; qc < 4; qc++) {
        int r = qc * 32 + rr;
        gA[qc] = A + (size_t)(m0 + r) * K + cshort;
        ldsoA[qc] = r * 64 + ((gc ^ (r & 7)) * 8);
    }
#pragma unroll
    for (int qc = 0; qc < NI; qc++) {
        int r = qc * 32 + rr;
        gB[qc] = Bt + (size_t)(n0 + r) * K + cshort;
        ldsoB[qc] = r * 64 + ((gc ^ (r & 7)) * 8);
    }

    floatx4 acc[4][NI] = {};
    const int sA = l16 & 7;

    shortx8 ra[4], rb[NI];
#pragma unroll
    for (int qc = 0; qc < 4; qc++) ra[qc] = *(const shortx8*)gA[qc];
#pragma unroll
    for (int qc = 0; qc < NI; qc++) rb[qc] = *(const shortx8*)gB[qc];

    for (int k0 = 0; k0 < K; k0 += 64) {
        __syncthreads();
#pragma unroll
        for (int qc = 0; qc < 4; qc++) *(shortx8*)&As[ldsoA[qc]] = ra[qc];
#pragma unroll
        for (int qc = 0; qc < NI; qc++) *(shortx8*)&Bs[ldsoB[qc]] = rb[qc];
        __syncthreads();
        if (k0 + 64 < K) {
#pragma unroll
            for (int qc = 0; qc < 4; qc++) ra[qc] = *(const shortx8*)(gA[qc] + k0 + 64);
#pragma unroll
            for (int qc = 0; qc < NI; qc++) rb[qc] = *(const shortx8*)(gB[qc] + k0 + 64);
        }
#pragma unroll
        for (int kkc = 0; kkc < 2; kkc++) {
            shortx8 af[4], bfr[NI];
            int slot = ((quad + kkc * 4) ^ sA) * 8;
#pragma unroll
            for (int i = 0; i < 4; i++)
                af[i] = *(const shortx8*)&As[(wm + i * 16 + l16) * 64 + slot];
#pragma unroll
            for (int i = 0; i < NI; i++)
                bfr[i] = *(const shortx8*)&Bs[(wn + i * 16 + l16) * 64 + slot];
#pragma unroll
            for (int mi = 0; mi < 4; mi++)
#pragma unroll
                for (int ni = 0; ni < NI; ni++)
                    acc[mi][ni] = __builtin_amdgcn_mfma_f32_16x16x32_bf16(af[mi], bfr[ni], acc[mi][ni], 0, 0, 0);
        }
    }

    const int seg = (MODE == 0) ? (n0 / DIM) : 0;
#pragma unroll
    for (int mi = 0; mi < 4; mi++) {
        int mrow0 = m0 + wm + mi * 16 + quad * 4;
        int4 mk4 = {0, 0, 0, 0};
        if (MODE == 2 || MODE == 3) mk4 = *(const int4*)&mask[mrow0];
#pragma unroll
        for (int ni = 0; ni < NI; ni++) {
            int n = n0 + wn + ni * 16 + l16;
            float bv = bias[n];
            float vals[4];
#pragma unroll
            for (int reg = 0; reg < 4; reg++) vals[reg] = acc[mi][ni][reg] + bv;
            if (MODE == 0) {
                int nl = n - seg * DIM;
                if (seg == 2) {
                    // V^T [b,h,d,T*64+key_new], key_new = 4*(key%16)+key/16
                    int hh = nl / HD, d = nl - hh * HD;
                    int bb = mrow0 / NN, nb = mrow0 - bb * NN;
                    int T = nb >> 6, ko = nb & 63;
                    int c16 = ko & 15, kb = ko >> 4;
                    short* vp = o2 + ((size_t)((bb * HEADS + hh) * HD + d)) * NN + T * 64 + kb;
#pragma unroll
                    for (int reg = 0; reg < 4; reg++) vp[4 * (c16 + reg)] = f2bf(vals[reg]);
                } else {
                    short* dstq = (seg == 0) ? o0 : o1;
                    int pc = nl % HD;
#pragma unroll
                    for (int reg = 0; reg < 4; reg++) {
                        int m = mrow0 + reg;
                        float val = vals[reg];
                        if (seg == 1) val += pe[(size_t)m * HD + pc];
                        dstq[(size_t)m * DIM + nl] = f2bf(val);
                    }
                }
            } else if (MODE == 1) {
#pragma unroll
                for (int reg = 0; reg < 4; reg++)
                    o0[(size_t)(mrow0 + reg) * N + n] = f2bf(gelu_exact(vals[reg]));
            } else if (MODE == 2) {
#pragma unroll
                for (int reg = 0; reg < 4; reg++) {
                    int m = mrow0 + reg;
                    int mk = ((const int*)&mk4)[reg];
                    of[(size_t)m * N + n] = res[(size_t)m * N + n] + (mk ? vals[reg] : 0.f);
                }
            } else {
#pragma unroll
                for (int reg = 0; reg < 4; reg++) {
                    int m = mrow0 + reg;
                    int mk = ((const int*)&mk4)[reg];
                    of[(size_t)m * N + n] = mk ? (res[(size_t)m * N + n] + vals[reg]) : 0.f;
                }
            }
        }
    }
}

// ---------------- MFMA flash attention v5: split-K over 2 halves ----------------
// Each block: 64 queries x 1024 keys (16 tiles). No-max softmax => partials combine
// by plain addition (no rescale): O = (O0+O1)/(l0+l1). Partials fp32.
__global__ __launch_bounds__(256) void attn5_kernel(const short* __restrict__ q,
                                                    const short* __restrict__ k,
                                                    const short* __restrict__ vt,
                                                    const int* __restrict__ mask,
                                                    float* __restrict__ Opart0,
                                                    float* __restrict__ Opart1,
                                                    float* __restrict__ lpart) {
    const int b = blockIdx.z >> 1, half = blockIdx.z & 1;
    const int kbase = half * (NN / 2);
    const int q0 = blockIdx.x * 64;
    const int h = blockIdx.y;
    const int t = threadIdx.x;
    const int lane = t & 63;
    const int w = t >> 6;
    const int l16 = lane & 15;
    const int quad = lane >> 4;

    // SH: Ks [64][72] @0, Vt [48][72] @4608, Pl 4x[16][72] @8064
    __shared__ __align__(16) short SH[12672];
    __shared__ float madd2[64];

    if (t < 128) {
        shortx8 z = {0, 0, 0, 0, 0, 0, 0, 0};
        *(shortx8*)&SH[(t >> 1) * 72 + 48 + (t & 1) * 8] = z;
    }

    const size_t vtbase = (size_t)((b * HEADS + h) * HD) * NN;
    const short* gsrc[3]; int loff[3]; int gstep[3];
#pragma unroll
    for (int i = 0; i < 3; i++) {
        int u = t + i * 256;
        if (u < 384) {
            int r = u / 6, c = u - r * 6;
            gsrc[i] = k + ((size_t)(b * NN + kbase + r)) * DIM + h * HD + c * 8;
            gstep[i] = 64 * DIM;
            loff[i] = r * 72 + c * 8;
        } else {
            int uu = u - 384;
            int r = uu >> 3, c = uu & 7;
            gsrc[i] = vt + vtbase + (size_t)r * NN + kbase + c * 8;
            gstep[i] = 64;
            loff[i] = 4608 + r * 72 + c * 8;
        }
    }
    shortx8 pre[3];
#pragma unroll
    for (int i = 0; i < 3; i++) pre[i] = *(const shortx8*)gsrc[i];
    int mreg = (t < 64) ? mask[b * NN + kbase + t] : 0;

    shortx8 qf0, qf1 = {0, 0, 0, 0, 0, 0, 0, 0};
    {
        const short* qp = q + ((size_t)(b * NN + q0 + w * 16 + l16)) * DIM + h * HD;
        qf0 = *(const shortx8*)&qp[quad * 8];
        if (quad < 2) qf1 = *(const shortx8*)&qp[32 + quad * 8];
    }

    floatx4 acc[3] = {{0.f, 0.f, 0.f, 0.f}, {0.f, 0.f, 0.f, 0.f}, {0.f, 0.f, 0.f, 0.f}};
    float lsum[4] = {0.f, 0.f, 0.f, 0.f};
    const float c1 = 0.14433756729740643f * 1.4426950408889634f;  // scale * log2(e)
    const int plbase = 8064 + w * 1152;

    for (int kk = 0; kk < 16; kk++) {
        __syncthreads();
#pragma unroll
        for (int i = 0; i < 3; i++) *(shortx8*)&SH[loff[i]] = pre[i];
        if (t < 64) madd2[t] = mreg ? 0.f : -1e30f;
        __syncthreads();
        if (kk < 15) {
#pragma unroll
            for (int i = 0; i < 3; i++) { gsrc[i] += gstep[i]; pre[i] = *(const shortx8*)gsrc[i]; }
            if (t < 64) mreg = mask[b * NN + kbase + (kk + 1) * 64 + t];
        }

        floatx4 S[4];
#pragma unroll
        for (int nt = 0; nt < 4; nt++) {
            shortx8 kb0 = *(const shortx8*)&SH[(nt * 16 + l16) * 72 + quad * 8];
            shortx8 kb1 = *(const shortx8*)&SH[(nt * 16 + l16) * 72 + 32 + quad * 8];
            floatx4 s = {0.f, 0.f, 0.f, 0.f};
            s = __builtin_amdgcn_mfma_f32_16x16x32_bf16(qf0, kb0, s, 0, 0, 0);
            s = __builtin_amdgcn_mfma_f32_16x16x32_bf16(qf1, kb1, s, 0, 0, 0);
            S[nt] = s;
        }
        float p[4][4];
#pragma unroll
        for (int nt = 0; nt < 4; nt++) {
            float ad = madd2[nt * 16 + l16];
#pragma unroll
            for (int reg = 0; reg < 4; reg++) {
                float pv = exp2f(S[nt][reg] * c1 + ad);
                p[nt][reg] = pv;
                lsum[reg] += pv;
            }
        }
#pragma unroll
        for (int reg = 0; reg < 4; reg++) {
            __hip_bfloat162 lo = __float22bfloat162_rn(make_float2(p[0][reg], p[1][reg]));
            __hip_bfloat162 hi = __float22bfloat162_rn(make_float2(p[2][reg], p[3][reg]));
            *(uint2*)&SH[plbase + (quad * 4 + reg) * 72 + l16 * 4] =
                make_uint2(*(unsigned*)&lo, *(unsigned*)&hi);
        }
#pragma unroll
        for (int c = 0; c < 2; c++) {
            shortx8 pf = *(const shortx8*)&SH[plbase + l16 * 72 + c * 32 + quad * 8];
#pragma unroll
            for (int dt = 0; dt < 3; dt++) {
                shortx8 vf = *(const shortx8*)&SH[4608 + (dt * 16 + l16) * 72 + c * 32 + quad * 8];
                acc[dt] = __builtin_amdgcn_mfma_f32_16x16x32_bf16(pf, vf, acc[dt], 0, 0, 0);
            }
        }
    }

    // partial epilogue: store unnormalized O (fp32) and l
    float* Op = half ? Opart1 : Opart0;
#pragma unroll
    for (int reg = 0; reg < 4; reg++) {
        float s = lsum[reg];
#pragma unroll
        for (int off = 1; off < 16; off <<= 1) s += __shfl_xor(s, off, 64);
        if (l16 == 0) {
            size_t row = (size_t)(b * NN + q0 + w * 16 + quad * 4 + reg);
            lpart[((size_t)half * ROWS + row) * HEADS + h] = s;
        }
    }
#pragma unroll
    for (int dt = 0; dt < 3; dt++)
#pragma unroll
        for (int reg = 0; reg < 4; reg++) {
            size_t row = (size_t)(b * NN + q0 + w * 16 + quad * 4 + reg);
            Op[row * DIM + h * HD + dt * 16 + l16] = acc[dt][reg];
        }
}

// ---------------- combine: attn_bf = (O0+O1)/(l0+l1), fp32 -> bf16 ----------------
__global__ __launch_bounds__(256) void combine_kernel(const float* __restrict__ O0,
                                                      const float* __restrict__ O1,
                                                      const float* __restrict__ lp,
                                                      short* __restrict__ out) {
    int i4 = blockIdx.x * 256 + threadIdx.x;
    int base = i4 * 4;
    int row = base / DIM;
    int c = base - row * DIM;
    int h = c / HD;
    float4 a = *(const float4*)&O0[base];
    float4 b = *(const float4*)&O1[base];
    float l = lp[(size_t)row * HEADS + h] + lp[((size_t)ROWS + row) * HEADS + h];
    float r = 1.f / l;
    short4 s = make_short4(f2bf((a.x + b.x) * r), f2bf((a.y + b.y) * r),
                           f2bf((a.z + b.z) * r), f2bf((a.w + b.w) * r));
    *(short4*)&out[base] = s;
}

extern "C" void kernel_launch(void* const* d_in, const int* in_sizes, int n_in,
                              void* d_out, int out_size, void* d_ws, size_t ws_size,
                              hipStream_t stream) {
    const float* x   = (const float*)d_in[0];
    const float* pos = (const float*)d_in[1];
    const int*   mask= (const int*)  d_in[2];
    const float* Wq  = (const float*)d_in[3];
    const float* bq  = (const float*)d_in[4];
    const float* Wk  = (const float*)d_in[5];
    const float* bk  = (const float*)d_in[6];
    const float* Wv  = (const float*)d_in[7];
    const float* bv  = (const float*)d_in[8];
    const float* pw1 = (const float*)d_in[9];
    const float* pb1 = (const float*)d_in[10];
    const float* pw2 = (const float*)d_in[11];
    const float* pb2 = (const float*)d_in[12];
    const float* Wo  = (const float*)d_in[13];
    const float* bo  = (const float*)d_in[14];
    const float* mw1 = (const float*)d_in[15];
    const float* mb1 = (const float*)d_in[16];
    const float* mw2 = (const float*)d_in[17];
    const float* mb2 = (const float*)d_in[18];
    const float* g1  = (const float*)d_in[19];
    const float* be1 = (const float*)d_in[20];
    const float* g2  = (const float*)d_in[21];
    const float* be2 = (const float*)d_in[22];
    float* out = (float*)d_out;

    // workspace layout (bytes); total use 69206016 < 77070336 proven in round 0
    char* wsb = (char*)d_ws;
    short* h_bf    = (short*)(wsb + 0);           // 6291456
    short* q_bf    = (short*)(wsb + 6291456);
    short* k_bf    = (short*)(wsb + 12582912);
    short* vt_bf   = (short*)(wsb + 18874368);    // V^T [b][h][d][n], key-permuted
    short* attn_bf = (short*)(wsb + 25165824);
    short* mlph_bf = h_bf;                        // overlays h|q|k|vt (dead by MLP1)
    float* pebuf   = (float*)(wsb + 31457280);    // 1572864
    float* x1      = (float*)(wsb + 33030144);    // 12582912
    short* h2_bf   = (short*)(wsb + 45613056);    // 6291456
    short* Wqkv_t  = (short*)(wsb + 51904512);    // [1152][384] bf16
    short* Wo_t    = (short*)(wsb + 52789248);    // [384][384]
    short* mw1_t   = (short*)(wsb + 53084160);    // [1536][384]
    short* mw2_t   = (short*)(wsb + 54263808);    // [384][1536]
    float* bqkv    = (float*)(wsb + 55443456);    // [1152]
    float* lpart   = (float*)(wsb + 55448064);    // [2][ROWS][HEADS] = 524288
    float* Opart0  = x1;                          // overlays x1 (dead until Wo epilogue)
    float* Opart1  = (float*)(wsb + 56623104);    // 12582912 -> end 69206016

    // --- fused weight prep (1 launch) ---
    prep_kernel<<<1729, 256, 0, stream>>>(Wq, Wk, Wv, Wo, mw1, mw2, bq, bk, bv,
                                          Wqkv_t, Wo_t, mw1_t, mw2_t, bqkv);

    // --- main pipeline ---
    ln_bf16_kernel<<<ROWS / 4, 256, 0, stream>>>(x, g1, be1, h_bf);
    pe_kernel<<<ROWS / 4, 256, 0, stream>>>(pos, pw1, pb1, pw2, pb2, pebuf);

    // fused QKV: [8192,1152] = h @ [Wq|Wk|Wv]; epilogue: q/k row-major (+pe on k), V^T permuted
    gemm3_kernel<0, 128><<<dim3(3 * DIM / 128, ROWS / 128), 256, 0, stream>>>(
        h_bf, Wqkv_t, bqkv, pebuf, nullptr, nullptr, nullptr, q_bf, k_bf, vt_bf,
        ROWS, 3 * DIM, DIM);

    // split-K attention: 2048 blocks
    attn5_kernel<<<dim3(NN / 64, HEADS, BB * 2), 256, 0, stream>>>(
        q_bf, k_bf, vt_bf, mask, Opart0, Opart1, lpart);
    combine_kernel<<<(int)(SZ / 4 / 256), 256, 0, stream>>>(Opart0, Opart1, lpart, attn_bf);

    // Wo + residual + mask -> x1 fp32
    gemm3_kernel<2, 128><<<dim3(DIM / 128, ROWS / 128), 256, 0, stream>>>(
        attn_bf, Wo_t, bo, nullptr, x, mask, x1, nullptr, nullptr, nullptr,
        ROWS, DIM, DIM);

    ln_bf16_kernel<<<ROWS / 4, 256, 0, stream>>>(x1, g2, be2, h2_bf);

    // MLP1 (exact gelu) -> bf16 hidden
    gemm3_kernel<1, 128><<<dim3(MLPH / 128, ROWS / 128), 256, 0, stream>>>(
        h2_bf, mw1_t, mb1, nullptr, nullptr, nullptr, nullptr, mlph_bf, nullptr, nullptr,
        ROWS, MLPH, DIM);

    // MLP2 + residual + mask -> out fp32
    gemm3_kernel<3, 128><<<dim3(DIM / 128, ROWS / 128), 256, 0, stream>>>(
        mlph_bf, mw2_t, mb2, nullptr, x1, mask, out, nullptr, nullptr, nullptr,
        ROWS, DIM, MLPH);
}

// Round 8
// 296.849 us; speedup vs baseline: 1.0209x; 1.0209x over previous
//
#include <hip/hip_runtime.h>
#include <hip/hip_bf16.h>
#include <math.h>

// Problem constants
#define BB 4
#define NN 2048
#define DIM 384
#define HEADS 8
#define HD 48
#define MLPH 1536
#define ROWS (BB*NN)          // 8192
#define SZ ((size_t)ROWS*DIM) // 3145728 elems per (B,N,DIM) buffer

typedef float floatx4 __attribute__((ext_vector_type(4)));
typedef short shortx8 __attribute__((ext_vector_type(8)));

__device__ __forceinline__ float gelu_exact(float x) {
    return 0.5f * x * (1.0f + erff(x * 0.70710678118654752f));
}

__device__ __forceinline__ short f2bf(float f) {
    __hip_bfloat16 h = __float2bfloat16(f);
    return *reinterpret_cast<short*>(&h);
}

// ---------------- LayerNorm: 4 rows/block (one wave each), fp32 -> bf16 ----------------
__global__ __launch_bounds__(256) void ln_bf16_kernel(const float* __restrict__ x,
                                                      const float* __restrict__ g,
                                                      const float* __restrict__ be,
                                                      short* __restrict__ out) {
    int row = blockIdx.x * 4 + (threadIdx.x >> 6);
    int lane = threadIdx.x & 63;
    const float* xp = x + (size_t)row * DIM;
    float v[6];
    float sum = 0.f, sumsq = 0.f;
#pragma unroll
    for (int j = 0; j < 6; j++) {
        float val = xp[lane + j * 64];
        v[j] = val; sum += val; sumsq += val * val;
    }
#pragma unroll
    for (int off = 1; off < 64; off <<= 1) {
        sum += __shfl_xor(sum, off, 64);
        sumsq += __shfl_xor(sumsq, off, 64);
    }
    float mean = sum * (1.f / DIM);
    float var = sumsq * (1.f / DIM) - mean * mean;
    float rstd = rsqrtf(var + 1e-5f);
    short* op = out + (size_t)row * DIM;
#pragma unroll
    for (int j = 0; j < 6; j++) {
        int c = lane + j * 64;
        op[c] = f2bf((v[j] - mean) * rstd * g[c] + be[c]);
    }
}

// ---------------- positional MLP: 4 points/block, pw2 staged in LDS ----------------
__global__ __launch_bounds__(256) void pe_kernel(const float* __restrict__ pos,
                                                 const float* __restrict__ pw1,
                                                 const float* __restrict__ pb1,
                                                 const float* __restrict__ pw2,
                                                 const float* __restrict__ pb2,
                                                 float* __restrict__ pe) {
    __shared__ float pw2s[HD * HD];
    __shared__ float hsh[4][HD];
    int t = threadIdx.x;
    int w = t >> 6, lane = t & 63;
    int p = blockIdx.x * 4 + w;
    for (int i = t; i < HD * HD; i += 256) pw2s[i] = pw2[i];
    float px = pos[(size_t)p * 3 + 0];
    float py = pos[(size_t)p * 3 + 1];
    float pz = pos[(size_t)p * 3 + 2];
    __syncthreads();
    if (lane < HD) {
        float hv = px * pw1[0 * HD + lane] + py * pw1[1 * HD + lane] + pz * pw1[2 * HD + lane] + pb1[lane];
        hsh[w][lane] = gelu_exact(hv);
    }
    if (lane < HD) {
        float o = pb2[lane];
#pragma unroll 8
        for (int i = 0; i < HD; i++) o += hsh[w][i] * pw2s[i * HD + lane];
        pe[(size_t)p * HD + lane] = o;
    }
}

// ---------------- fused weight prep: all transposes (fp32 [K][N] -> bf16 [N][K]) + bias ----
__global__ __launch_bounds__(256) void prep_kernel(const float* __restrict__ Wq,
                                                   const float* __restrict__ Wk,
                                                   const float* __restrict__ Wv,
                                                   const float* __restrict__ Wo,
                                                   const float* __restrict__ mw1,
                                                   const float* __restrict__ mw2,
                                                   const float* __restrict__ bq,
                                                   const float* __restrict__ bk,
                                                   const float* __restrict__ bv,
                                                   short* __restrict__ Wqkv_t,
                                                   short* __restrict__ Wo_t,
                                                   short* __restrict__ mw1_t,
                                                   short* __restrict__ mw2_t,
                                                   float* __restrict__ bqkv) {
    __shared__ float tile[32][33];
    int id = blockIdx.x;
    if (id >= 1728) {  // bias concat
        for (int i = threadIdx.x; i < 3 * DIM; i += 256)
            bqkv[i] = i < DIM ? bq[i] : (i < 2 * DIM ? bk[i - DIM] : bv[i - 2 * DIM]);
        return;
    }
    const float* src; short* dst; int K, N, tid;
    if (id < 144)       { src = Wq;  dst = Wqkv_t;               K = 384;  N = 384;  tid = id; }
    else if (id < 288)  { src = Wk;  dst = Wqkv_t + 147456;      K = 384;  N = 384;  tid = id - 144; }
    else if (id < 432)  { src = Wv;  dst = Wqkv_t + 294912;      K = 384;  N = 384;  tid = id - 288; }
    else if (id < 576)  { src = Wo;  dst = Wo_t;                 K = 384;  N = 384;  tid = id - 432; }
    else if (id < 1152) { src = mw1; dst = mw1_t;                K = 384;  N = 1536; tid = id - 576; }
    else                { src = mw2; dst = mw2_t;                K = 1536; N = 384;  tid = id - 1152; }
    int ntx = N / 32;
    int n0 = (tid % ntx) * 32, k0 = (tid / ntx) * 32;
    int c = threadIdx.x & 31, r4 = threadIdx.x >> 5;
#pragma unroll
    for (int i = 0; i < 4; i++) {
        int r = r4 + i * 8;
        tile[r][c] = src[(size_t)(k0 + r) * N + n0 + c];
    }
    __syncthreads();
#pragma unroll
    for (int i = 0; i < 4; i++) {
        int r = r4 + i * 8;
        dst[(size_t)(n0 + r) * K + k0 + c] = f2bf(tile[c][r]);
    }
}

// ---------------- bf16 MFMA GEMM v3: C[M,N] = A[M,K] @ Bt[N,K]^T + bias ----------------
// 128x128 tile, BK=64, 4 waves 2x2. XOR-8 swizzle + 1-tile register prefetch.
// Pure-DS two-barrier staging (round-3 lesson).
// MODE 0: QKV fused -> q/k row-major bf16 (pe added to k), V^T permuted:
//         key_new = 4*(key%16) + key/16 within each 64-key tile (matches attention).
// MODE 1: exact gelu -> bf16 (MLP1)
// MODE 2: of = res + (mask ? v : 0)  fp32 (Wo + residual)
// MODE 3: of = mask ? (res + v) : 0  fp32 (MLP2 + residual + mask)
template <int MODE, int TN>
__global__ __launch_bounds__(256) void gemm3_kernel(const short* __restrict__ A,
                                                    const short* __restrict__ Bt,
                                                    const float* __restrict__ bias,
                                                    const float* __restrict__ pe,
                                                    const float* __restrict__ res,
                                                    const int* __restrict__ mask,
                                                    float* __restrict__ of,
                                                    short* __restrict__ o0,
                                                    short* __restrict__ o1,
                                                    short* __restrict__ o2,
                                                    int M, int N, int K) {
    constexpr int NI = TN / 32;
    __shared__ short As[128 * 64];
    __shared__ short Bs[TN * 64];
    const int t = threadIdx.x, lane = t & 63, w = t >> 6;
    const int l16 = lane & 15, quad = lane >> 4;
    const int m0 = blockIdx.y * 128, n0 = blockIdx.x * TN;
    const int wm = (w & 1) * 64, wn = (w >> 1) * (TN / 2);

    const int rr = t >> 3, gc = t & 7, cshort = gc * 8;
    const short* gA[4]; int ldsoA[4];
    const short* gB[NI]; int ldsoB[NI];
#pragma unroll
    for (int qc = 0; qc < 4; qc++) {
        int r = qc * 32 + rr;
        gA[qc] = A + (size_t)(m0 + r) * K + cshort;
        ldsoA[qc] = r * 64 + ((gc ^ (r & 7)) * 8);
    }
#pragma unroll
    for (int qc = 0; qc < NI; qc++) {
        int r = qc * 32 + rr;
        gB[qc] = Bt + (size_t)(n0 + r) * K + cshort;
        ldsoB[qc] = r * 64 + ((gc ^ (r & 7)) * 8);
    }

    floatx4 acc[4][NI] = {};
    const int sA = l16 & 7;

    shortx8 ra[4], rb[NI];
#pragma unroll
    for (int qc = 0; qc < 4; qc++) ra[qc] = *(const shortx8*)gA[qc];
#pragma unroll
    for (int qc = 0; qc < NI; qc++) rb[qc] = *(const shortx8*)gB[qc];

    for (int k0 = 0; k0 < K; k0 += 64) {
        __syncthreads();
#pragma unroll
        for (int qc = 0; qc < 4; qc++) *(shortx8*)&As[ldsoA[qc]] = ra[qc];
#pragma unroll
        for (int qc = 0; qc < NI; qc++) *(shortx8*)&Bs[ldsoB[qc]] = rb[qc];
        __syncthreads();
        if (k0 + 64 < K) {
#pragma unroll
            for (int qc = 0; qc < 4; qc++) ra[qc] = *(const shortx8*)(gA[qc] + k0 + 64);
#pragma unroll
            for (int qc = 0; qc < NI; qc++) rb[qc] = *(const shortx8*)(gB[qc] + k0 + 64);
        }
#pragma unroll
        for (int kkc = 0; kkc < 2; kkc++) {
            shortx8 af[4], bfr[NI];
            int slot = ((quad + kkc * 4) ^ sA) * 8;
#pragma unroll
            for (int i = 0; i < 4; i++)
                af[i] = *(const shortx8*)&As[(wm + i * 16 + l16) * 64 + slot];
#pragma unroll
            for (int i = 0; i < NI; i++)
                bfr[i] = *(const shortx8*)&Bs[(wn + i * 16 + l16) * 64 + slot];
#pragma unroll
            for (int mi = 0; mi < 4; mi++)
#pragma unroll
                for (int ni = 0; ni < NI; ni++)
                    acc[mi][ni] = __builtin_amdgcn_mfma_f32_16x16x32_bf16(af[mi], bfr[ni], acc[mi][ni], 0, 0, 0);
        }
    }

    const int seg = (MODE == 0) ? (n0 / DIM) : 0;
#pragma unroll
    for (int mi = 0; mi < 4; mi++) {
        int mrow0 = m0 + wm + mi * 16 + quad * 4;
        int4 mk4 = {0, 0, 0, 0};
        if (MODE == 2 || MODE == 3) mk4 = *(const int4*)&mask[mrow0];
#pragma unroll
        for (int ni = 0; ni < NI; ni++) {
            int n = n0 + wn + ni * 16 + l16;
            float bv = bias[n];
            float vals[4];
#pragma unroll
            for (int reg = 0; reg < 4; reg++) vals[reg] = acc[mi][ni][reg] + bv;
            if (MODE == 0) {
                int nl = n - seg * DIM;
                if (seg == 2) {
                    // V^T [b,h,d,T*64+key_new], key_new = 4*(key%16)+key/16
                    int hh = nl / HD, d = nl - hh * HD;
                    int bb = mrow0 / NN, nb = mrow0 - bb * NN;
                    int T = nb >> 6, ko = nb & 63;
                    int c16 = ko & 15, kb = ko >> 4;
                    short* vp = o2 + ((size_t)((bb * HEADS + hh) * HD + d)) * NN + T * 64 + kb;
#pragma unroll
                    for (int reg = 0; reg < 4; reg++) vp[4 * (c16 + reg)] = f2bf(vals[reg]);
                } else {
                    short* dstq = (seg == 0) ? o0 : o1;
                    int pc = nl % HD;
#pragma unroll
                    for (int reg = 0; reg < 4; reg++) {
                        int m = mrow0 + reg;
                        float val = vals[reg];
                        if (seg == 1) val += pe[(size_t)m * HD + pc];
                        dstq[(size_t)m * DIM + nl] = f2bf(val);
                    }
                }
            } else if (MODE == 1) {
#pragma unroll
                for (int reg = 0; reg < 4; reg++)
                    o0[(size_t)(mrow0 + reg) * N + n] = f2bf(gelu_exact(vals[reg]));
            } else if (MODE == 2) {
#pragma unroll
                for (int reg = 0; reg < 4; reg++) {
                    int m = mrow0 + reg;
                    int mk = ((const int*)&mk4)[reg];
                    of[(size_t)m * N + n] = res[(size_t)m * N + n] + (mk ? vals[reg] : 0.f);
                }
            } else {
#pragma unroll
                for (int reg = 0; reg < 4; reg++) {
                    int m = mrow0 + reg;
                    int mk = ((const int*)&mk4)[reg];
                    of[(size_t)m * N + n] = mk ? (res[(size_t)m * N + n] + vals[reg]) : 0.f;
                }
            }
        }
    }
}

// ---------------- MFMA flash attention v6 ----------------
// 128-query blocks (4 waves x 32 queries): shared K/V tile serves 2x queries vs v4,
// halving per-query LDS traffic. K/V LDS XOR-swizzled (chunk slot = c^(r&7), row
// stride 64 shorts): staging writes + frag reads bank-uniform; K zero-pad chunks land
// on disjoint slots, written once. Register-prefetched staging; no-max softmax.
__global__ __launch_bounds__(256) void attn6_kernel(const short* __restrict__ q,
                                                    const short* __restrict__ k,
                                                    const short* __restrict__ vt,
                                                    const int* __restrict__ mask,
                                                    short* __restrict__ out) {
    const int b = blockIdx.z, h = blockIdx.y;
    const int q0 = blockIdx.x * 128;
    const int t = threadIdx.x;
    const int lane = t & 63;
    const int w = t >> 6;
    const int l16 = lane & 15;
    const int quad = lane >> 4;

    // LDS (shorts): KS [64 keys][64 dims] @0 (swizzled), VT [48 dims][64 keys] @4096
    // (swizzled), PL per-wave [32 q][72] @7168 + w*2304. Total 32 KB + madd2.
    __shared__ __align__(16) short SH[16384];
    __shared__ float madd2[64];

    // one-time zero chunks of KS (dims 48..63): slots {6^(r&7), 7^(r&7)} per row —
    // disjoint from data slots {0..5}^(r&7), so never overwritten.
    if (t < 128) {
        int r = t >> 1, zc = 6 + (t & 1);
        shortx8 z = {0, 0, 0, 0, 0, 0, 0, 0};
        *(shortx8*)&SH[r * 64 + ((zc ^ (r & 7)) * 8)] = z;
    }

    // staging plan: 768 chunk tasks (K 384 + V 384), 3 per thread, loop-invariant
    const size_t vtbase = (size_t)((b * HEADS + h) * HD) * NN;
    const short* gsrc[3]; int loff[3]; int gstep[3];
#pragma unroll
    for (int i = 0; i < 3; i++) {
        int u = t + i * 256;
        if (u < 384) {
            int r = u / 6, c = u - r * 6;
            gsrc[i] = k + ((size_t)(b * NN + r)) * DIM + h * HD + c * 8;
            gstep[i] = 64 * DIM;
            loff[i] = r * 64 + ((c ^ (r & 7)) * 8);
        } else {
            int uu = u - 384;
            int d = uu >> 3, ck = uu & 7;
            gsrc[i] = vt + vtbase + (size_t)d * NN + ck * 8;
            gstep[i] = 64;
            loff[i] = 4096 + d * 64 + ((ck ^ (d & 7)) * 8);
        }
    }
    shortx8 pre[3];
#pragma unroll
    for (int i = 0; i < 3; i++) pre[i] = *(const shortx8*)gsrc[i];
    int mreg = (t < 64) ? mask[b * NN + t] : 0;

    // Q A-fragments for 2 m-tiles (wave owns queries q0+w*32 .. +32)
    shortx8 qf[2][2];
#pragma unroll
    for (int mt = 0; mt < 2; mt++) {
        const short* qp = q + ((size_t)(b * NN + q0 + w * 32 + mt * 16 + l16)) * DIM + h * HD;
        qf[mt][0] = *(const shortx8*)&qp[quad * 8];
        if (quad < 2) qf[mt][1] = *(const shortx8*)&qp[32 + quad * 8];
        else          qf[mt][1] = (shortx8){0, 0, 0, 0, 0, 0, 0, 0};
    }

    floatx4 acc[2][3] = {};
    float lsum[2][4] = {};
    const float c1 = 0.14433756729740643f * 1.4426950408889634f;  // scale * log2(e)
    const int plb = 7168 + w * 2304;
    const int sw = (l16 & 7);

    for (int kt = 0; kt < 32; kt++) {
        __syncthreads();
#pragma unroll
        for (int i = 0; i < 3; i++) *(shortx8*)&SH[loff[i]] = pre[i];
        if (t < 64) madd2[t] = mreg ? 0.f : -1e30f;
        __syncthreads();
        if (kt < 31) {
#pragma unroll
            for (int i = 0; i < 3; i++) { gsrc[i] += gstep[i]; pre[i] = *(const shortx8*)gsrc[i]; }
            if (t < 64) mreg = mask[b * NN + (kt + 1) * 64 + t];
        }

        // QK^T: S[mt][q=quad*4+reg][key=nt*16+l16]
        floatx4 S[2][4];
#pragma unroll
        for (int nt = 0; nt < 4; nt++) {
            int r = nt * 16 + l16;
            shortx8 kb0 = *(const shortx8*)&SH[r * 64 + ((quad ^ sw) * 8)];
            shortx8 kb1 = *(const shortx8*)&SH[r * 64 + (((4 + quad) ^ sw) * 8)];
#pragma unroll
            for (int mt = 0; mt < 2; mt++) {
                floatx4 s = {0.f, 0.f, 0.f, 0.f};
                s = __builtin_amdgcn_mfma_f32_16x16x32_bf16(qf[mt][0], kb0, s, 0, 0, 0);
                s = __builtin_amdgcn_mfma_f32_16x16x32_bf16(qf[mt][1], kb1, s, 0, 0, 0);
                S[mt][nt] = s;
            }
        }
        // softmax-lite + packed P store (cols key_new = 4*l16+nt)
#pragma unroll
        for (int mt = 0; mt < 2; mt++) {
            float p[4][4];
#pragma unroll
            for (int nt = 0; nt < 4; nt++) {
                float ad = madd2[nt * 16 + l16];
#pragma unroll
                for (int reg = 0; reg < 4; reg++) {
                    float pv = exp2f(S[mt][nt][reg] * c1 + ad);
                    p[nt][reg] = pv;
                    lsum[mt][reg] += pv;
                }
            }
#pragma unroll
            for (int reg = 0; reg < 4; reg++) {
                __hip_bfloat162 lo = __float22bfloat162_rn(make_float2(p[0][reg], p[1][reg]));
                __hip_bfloat162 hi = __float22bfloat162_rn(make_float2(p[2][reg], p[3][reg]));
                *(uint2*)&SH[plb + (mt * 16 + quad * 4 + reg) * 72 + l16 * 4] =
                    make_uint2(*(unsigned*)&lo, *(unsigned*)&hi);
            }
        }
        // PV over key_new axis (V^T pre-permuted to match)
#pragma unroll
        for (int c = 0; c < 2; c++) {
            shortx8 pf[2];
#pragma unroll
            for (int mt = 0; mt < 2; mt++)
                pf[mt] = *(const shortx8*)&SH[plb + (mt * 16 + l16) * 72 + c * 32 + quad * 8];
#pragma unroll
            for (int dt = 0; dt < 3; dt++) {
                shortx8 vf = *(const shortx8*)&SH[4096 + (dt * 16 + l16) * 64 + (((c * 4 + quad) ^ sw) * 8)];
#pragma unroll
                for (int mt = 0; mt < 2; mt++)
                    acc[mt][dt] = __builtin_amdgcn_mfma_f32_16x16x32_bf16(pf[mt], vf, acc[mt][dt], 0, 0, 0);
            }
        }
    }

    // final: reduce l across the 16 key-columns, scale, store bf16
#pragma unroll
    for (int mt = 0; mt < 2; mt++)
#pragma unroll
        for (int reg = 0; reg < 4; reg++) {
            float s = lsum[mt][reg];
#pragma unroll
            for (int off = 1; off < 16; off <<= 1) s += __shfl_xor(s, off, 64);
            lsum[mt][reg] = 1.f / s;
        }
#pragma unroll
    for (int mt = 0; mt < 2; mt++)
#pragma unroll
        for (int dt = 0; dt < 3; dt++)
#pragma unroll
            for (int reg = 0; reg < 4; reg++) {
                size_t row = (size_t)(b * NN + q0 + w * 32 + mt * 16 + quad * 4 + reg);
                out[row * DIM + h * HD + dt * 16 + l16] = f2bf(acc[mt][dt][reg] * lsum[mt][reg]);
            }
}

extern "C" void kernel_launch(void* const* d_in, const int* in_sizes, int n_in,
                              void* d_out, int out_size, void* d_ws, size_t ws_size,
                              hipStream_t stream) {
    const float* x   = (const float*)d_in[0];
    const float* pos = (const float*)d_in[1];
    const int*   mask= (const int*)  d_in[2];
    const float* Wq  = (const float*)d_in[3];
    const float* bq  = (const float*)d_in[4];
    const float* Wk  = (const float*)d_in[5];
    const float* bk  = (const float*)d_in[6];
    const float* Wv  = (const float*)d_in[7];
    const float* bv  = (const float*)d_in[8];
    const float* pw1 = (const float*)d_in[9];
    const float* pb1 = (const float*)d_in[10];
    const float* pw2 = (const float*)d_in[11];
    const float* pb2 = (const float*)d_in[12];
    const float* Wo  = (const float*)d_in[13];
    const float* bo  = (const float*)d_in[14];
    const float* mw1 = (const float*)d_in[15];
    const float* mb1 = (const float*)d_in[16];
    const float* mw2 = (const float*)d_in[17];
    const float* mb2 = (const float*)d_in[18];
    const float* g1  = (const float*)d_in[19];
    const float* be1 = (const float*)d_in[20];
    const float* g2  = (const float*)d_in[21];
    const float* be2 = (const float*)d_in[22];
    float* out = (float*)d_out;

    // workspace layout (bytes)
    char* wsb = (char*)d_ws;
    short* h_bf    = (short*)(wsb + 0);           // 6291456
    short* q_bf    = (short*)(wsb + 6291456);
    short* k_bf    = (short*)(wsb + 12582912);
    short* vt_bf   = (short*)(wsb + 18874368);    // V^T [b][h][d][n], key-permuted
    short* attn_bf = (short*)(wsb + 25165824);
    short* mlph_bf = h_bf;                        // overlays h|q|k|vt (dead by MLP1)
    float* pebuf   = (float*)(wsb + 31457280);    // 1572864
    float* x1      = (float*)(wsb + 33030144);    // 12582912
    short* h2_bf   = (short*)(wsb + 45613056);    // 6291456
    short* Wqkv_t  = (short*)(wsb + 51904512);    // [1152][384] bf16
    short* Wo_t    = (short*)(wsb + 52789248);    // [384][384]
    short* mw1_t   = (short*)(wsb + 53084160);    // [1536][384]
    short* mw2_t   = (short*)(wsb + 54263808);    // [384][1536]
    float* bqkv    = (float*)(wsb + 55443456);    // [1152]

    // --- fused weight prep (1 launch) ---
    prep_kernel<<<1729, 256, 0, stream>>>(Wq, Wk, Wv, Wo, mw1, mw2, bq, bk, bv,
                                          Wqkv_t, Wo_t, mw1_t, mw2_t, bqkv);

    // --- main pipeline ---
    ln_bf16_kernel<<<ROWS / 4, 256, 0, stream>>>(x, g1, be1, h_bf);
    pe_kernel<<<ROWS / 4, 256, 0, stream>>>(pos, pw1, pb1, pw2, pb2, pebuf);

    // fused QKV: [8192,1152] = h @ [Wq|Wk|Wv]; epilogue: q/k row-major (+pe on k), V^T permuted
    gemm3_kernel<0, 128><<<dim3(3 * DIM / 128, ROWS / 128), 256, 0, stream>>>(
        h_bf, Wqkv_t, bqkv, pebuf, nullptr, nullptr, nullptr, q_bf, k_bf, vt_bf,
        ROWS, 3 * DIM, DIM);

    // attention: 512 blocks of 128 queries
    attn6_kernel<<<dim3(NN / 128, HEADS, BB), 256, 0, stream>>>(
        q_bf, k_bf, vt_bf, mask, attn_bf);

    // Wo + residual + mask -> x1 fp32
    gemm3_kernel<2, 128><<<dim3(DIM / 128, ROWS / 128), 256, 0, stream>>>(
        attn_bf, Wo_t, bo, nullptr, x, mask, x1, nullptr, nullptr, nullptr,
        ROWS, DIM, DIM);

    ln_bf16_kernel<<<ROWS / 4, 256, 0, stream>>>(x1, g2, be2, h2_bf);

    // MLP1 (exact gelu) -> bf16 hidden
    gemm3_kernel<1, 128><<<dim3(MLPH / 128, ROWS / 128), 256, 0, stream>>>(
        h2_bf, mw1_t, mb1, nullptr, nullptr, nullptr, nullptr, mlph_bf, nullptr, nullptr,
        ROWS, MLPH, DIM);

    // MLP2 + residual + mask -> out fp32
    gemm3_kernel<3, 128><<<dim3(DIM / 128, ROWS / 128), 256, 0, stream>>>(
        mlph_bf, mw2_t, mb2, nullptr, x1, mask, out, nullptr, nullptr, nullptr,
        ROWS, DIM, MLPH);
}

// Round 9
// 285.401 us; speedup vs baseline: 1.0619x; 1.0401x over previous
//
#include <hip/hip_runtime.h>
#include <hip/hip_bf16.h>
#include <math.h>

// Problem constants
#define BB 4
#define NN 2048
#define DIM 384
#define HEADS 8
#define HD 48
#define MLPH 1536
#define ROWS (BB*NN)          // 8192
#define SZ ((size_t)ROWS*DIM) // 3145728 elems per (B,N,DIM) buffer

typedef float floatx4 __attribute__((ext_vector_type(4)));
typedef short shortx8 __attribute__((ext_vector_type(8)));

__device__ __forceinline__ float gelu_exact(float x) {
    return 0.5f * x * (1.0f + erff(x * 0.70710678118654752f));
}

__device__ __forceinline__ short f2bf(float f) {
    __hip_bfloat16 h = __float2bfloat16(f);
    return *reinterpret_cast<short*>(&h);
}

// cheap bf16 pack: round-half-up on positive values (p = exp(..) >= 0)
__device__ __forceinline__ unsigned pkbf(float a, float b) {
    return ((__float_as_uint(a) + 0x8000u) >> 16) |
           ((__float_as_uint(b) + 0x8000u) & 0xFFFF0000u);
}
__device__ __forceinline__ short f2bf_c(float f) {
    return (short)((__float_as_uint(f) + 0x8000u) >> 16);
}

// ---------------- LayerNorm: 4 rows/block (one wave each), fp32 -> bf16 ----------------
__global__ __launch_bounds__(256) void ln_bf16_kernel(const float* __restrict__ x,
                                                      const float* __restrict__ g,
                                                      const float* __restrict__ be,
                                                      short* __restrict__ out) {
    int row = blockIdx.x * 4 + (threadIdx.x >> 6);
    int lane = threadIdx.x & 63;
    const float* xp = x + (size_t)row * DIM;
    float v[6];
    float sum = 0.f, sumsq = 0.f;
#pragma unroll
    for (int j = 0; j < 6; j++) {
        float val = xp[lane + j * 64];
        v[j] = val; sum += val; sumsq += val * val;
    }
#pragma unroll
    for (int off = 1; off < 64; off <<= 1) {
        sum += __shfl_xor(sum, off, 64);
        sumsq += __shfl_xor(sumsq, off, 64);
    }
    float mean = sum * (1.f / DIM);
    float var = sumsq * (1.f / DIM) - mean * mean;
    float rstd = rsqrtf(var + 1e-5f);
    short* op = out + (size_t)row * DIM;
#pragma unroll
    for (int j = 0; j < 6; j++) {
        int c = lane + j * 64;
        op[c] = f2bf((v[j] - mean) * rstd * g[c] + be[c]);
    }
}

// ---------------- fused head: weight transposes + bias concat + LN1 + pos-MLP ----------
// blocks [0,1728): W transposes (fp32 [K][N] -> bf16 [N][K]); 1728: bias concat;
// [1729,3777): LN1 (4 rows/blk); [3777,5825): pos-MLP (4 points/blk).
__global__ __launch_bounds__(256) void head_kernel(const float* __restrict__ Wq,
                                                   const float* __restrict__ Wk,
                                                   const float* __restrict__ Wv,
                                                   const float* __restrict__ Wo,
                                                   const float* __restrict__ mw1,
                                                   const float* __restrict__ mw2,
                                                   const float* __restrict__ bq,
                                                   const float* __restrict__ bk,
                                                   const float* __restrict__ bv,
                                                   const float* __restrict__ x,
                                                   const float* __restrict__ g1,
                                                   const float* __restrict__ be1,
                                                   const float* __restrict__ pos,
                                                   const float* __restrict__ pw1,
                                                   const float* __restrict__ pb1,
                                                   const float* __restrict__ pw2,
                                                   const float* __restrict__ pb2,
                                                   short* __restrict__ Wqkv_t,
                                                   short* __restrict__ Wo_t,
                                                   short* __restrict__ mw1_t,
                                                   short* __restrict__ mw2_t,
                                                   float* __restrict__ bqkv,
                                                   short* __restrict__ h_bf,
                                                   float* __restrict__ pe) {
    __shared__ float tile[32][33];
    __shared__ float pw2s[HD * HD];
    __shared__ float hsh[4][HD];
    const int id = blockIdx.x;
    const int t = threadIdx.x;
    if (id < 1728) {
        const float* src; short* dst; int K, N, tid;
        if (id < 144)       { src = Wq;  dst = Wqkv_t;          K = 384;  N = 384;  tid = id; }
        else if (id < 288)  { src = Wk;  dst = Wqkv_t + 147456; K = 384;  N = 384;  tid = id - 144; }
        else if (id < 432)  { src = Wv;  dst = Wqkv_t + 294912; K = 384;  N = 384;  tid = id - 288; }
        else if (id < 576)  { src = Wo;  dst = Wo_t;            K = 384;  N = 384;  tid = id - 432; }
        else if (id < 1152) { src = mw1; dst = mw1_t;           K = 384;  N = 1536; tid = id - 576; }
        else                { src = mw2; dst = mw2_t;           K = 1536; N = 384;  tid = id - 1152; }
        int ntx = N / 32;
        int n0 = (tid % ntx) * 32, k0 = (tid / ntx) * 32;
        int c = t & 31, r4 = t >> 5;
#pragma unroll
        for (int i = 0; i < 4; i++) {
            int r = r4 + i * 8;
            tile[r][c] = src[(size_t)(k0 + r) * N + n0 + c];
        }
        __syncthreads();
#pragma unroll
        for (int i = 0; i < 4; i++) {
            int r = r4 + i * 8;
            dst[(size_t)(n0 + r) * K + k0 + c] = f2bf(tile[c][r]);
        }
    } else if (id == 1728) {
        for (int i = t; i < 3 * DIM; i += 256)
            bqkv[i] = i < DIM ? bq[i] : (i < 2 * DIM ? bk[i - DIM] : bv[i - 2 * DIM]);
    } else if (id < 3777) {
        int row = (id - 1729) * 4 + (t >> 6);
        int lane = t & 63;
        const float* xp = x + (size_t)row * DIM;
        float v[6];
        float sum = 0.f, sumsq = 0.f;
#pragma unroll
        for (int j = 0; j < 6; j++) {
            float val = xp[lane + j * 64];
            v[j] = val; sum += val; sumsq += val * val;
        }
#pragma unroll
        for (int off = 1; off < 64; off <<= 1) {
            sum += __shfl_xor(sum, off, 64);
            sumsq += __shfl_xor(sumsq, off, 64);
        }
        float mean = sum * (1.f / DIM);
        float var = sumsq * (1.f / DIM) - mean * mean;
        float rstd = rsqrtf(var + 1e-5f);
        short* op = h_bf + (size_t)row * DIM;
#pragma unroll
        for (int j = 0; j < 6; j++) {
            int c = lane + j * 64;
            op[c] = f2bf((v[j] - mean) * rstd * g1[c] + be1[c]);
        }
    } else {
        int w = t >> 6, lane = t & 63;
        int p = (id - 3777) * 4 + w;
        for (int i = t; i < HD * HD; i += 256) pw2s[i] = pw2[i];
        float px = pos[(size_t)p * 3 + 0];
        float py = pos[(size_t)p * 3 + 1];
        float pz = pos[(size_t)p * 3 + 2];
        __syncthreads();
        if (lane < HD) {
            float hv = px * pw1[0 * HD + lane] + py * pw1[1 * HD + lane] + pz * pw1[2 * HD + lane] + pb1[lane];
            hsh[w][lane] = gelu_exact(hv);
        }
        if (lane < HD) {
            float o = pb2[lane];
#pragma unroll 8
            for (int i = 0; i < HD; i++) o += hsh[w][i] * pw2s[i * HD + lane];
            pe[(size_t)p * HD + lane] = o;
        }
    }
}

// ---------------- bf16 MFMA GEMM v3: C[M,N] = A[M,K] @ Bt[N,K]^T + bias ----------------
// 128x128 tile, BK=64, 4 waves 2x2. XOR-8 swizzle + 1-tile register prefetch.
// MODE 0: QKV fused -> q/k row-major bf16 (pe added to k), V^T permuted (key_new =
//         4*(key%16)+key/16 per 64-key tile, matching attention's packed-P layout).
// MODE 1: exact gelu -> bf16 (MLP1)
// MODE 2: of = res + (mask ? v : 0)  fp32 (Wo + residual)
// MODE 3: of = mask ? (res + v) : 0  fp32 (MLP2 + residual + mask)
template <int MODE, int TN>
__global__ __launch_bounds__(256) void gemm3_kernel(const short* __restrict__ A,
                                                    const short* __restrict__ Bt,
                                                    const float* __restrict__ bias,
                                                    const float* __restrict__ pe,
                                                    const float* __restrict__ res,
                                                    const int* __restrict__ mask,
                                                    float* __restrict__ of,
                                                    short* __restrict__ o0,
                                                    short* __restrict__ o1,
                                                    short* __restrict__ o2,
                                                    int M, int N, int K) {
    constexpr int NI = TN / 32;
    __shared__ short As[128 * 64];
    __shared__ short Bs[TN * 64];
    const int t = threadIdx.x, lane = t & 63, w = t >> 6;
    const int l16 = lane & 15, quad = lane >> 4;
    const int m0 = blockIdx.y * 128, n0 = blockIdx.x * TN;
    const int wm = (w & 1) * 64, wn = (w >> 1) * (TN / 2);

    const int rr = t >> 3, gc = t & 7, cshort = gc * 8;
    const short* gA[4]; int ldsoA[4];
    const short* gB[NI]; int ldsoB[NI];
#pragma unroll
    for (int qc = 0; qc < 4; qc++) {
        int r = qc * 32 + rr;
        gA[qc] = A + (size_t)(m0 + r) * K + cshort;
        ldsoA[qc] = r * 64 + ((gc ^ (r & 7)) * 8);
    }
#pragma unroll
    for (int qc = 0; qc < NI; qc++) {
        int r = qc * 32 + rr;
        gB[qc] = Bt + (size_t)(n0 + r) * K + cshort;
        ldsoB[qc] = r * 64 + ((gc ^ (r & 7)) * 8);
    }

    floatx4 acc[4][NI] = {};
    const int sA = l16 & 7;

    shortx8 ra[4], rb[NI];
#pragma unroll
    for (int qc = 0; qc < 4; qc++) ra[qc] = *(const shortx8*)gA[qc];
#pragma unroll
    for (int qc = 0; qc < NI; qc++) rb[qc] = *(const shortx8*)gB[qc];

    for (int k0 = 0; k0 < K; k0 += 64) {
        __syncthreads();
#pragma unroll
        for (int qc = 0; qc < 4; qc++) *(shortx8*)&As[ldsoA[qc]] = ra[qc];
#pragma unroll
        for (int qc = 0; qc < NI; qc++) *(shortx8*)&Bs[ldsoB[qc]] = rb[qc];
        __syncthreads();
        if (k0 + 64 < K) {
#pragma unroll
            for (int qc = 0; qc < 4; qc++) ra[qc] = *(const shortx8*)(gA[qc] + k0 + 64);
#pragma unroll
            for (int qc = 0; qc < NI; qc++) rb[qc] = *(const shortx8*)(gB[qc] + k0 + 64);
        }
#pragma unroll
        for (int kkc = 0; kkc < 2; kkc++) {
            shortx8 af[4], bfr[NI];
            int slot = ((quad + kkc * 4) ^ sA) * 8;
#pragma unroll
            for (int i = 0; i < 4; i++)
                af[i] = *(const shortx8*)&As[(wm + i * 16 + l16) * 64 + slot];
#pragma unroll
            for (int i = 0; i < NI; i++)
                bfr[i] = *(const shortx8*)&Bs[(wn + i * 16 + l16) * 64 + slot];
#pragma unroll
            for (int mi = 0; mi < 4; mi++)
#pragma unroll
                for (int ni = 0; ni < NI; ni++)
                    acc[mi][ni] = __builtin_amdgcn_mfma_f32_16x16x32_bf16(af[mi], bfr[ni], acc[mi][ni], 0, 0, 0);
        }
    }

    const int seg = (MODE == 0) ? (n0 / DIM) : 0;
#pragma unroll
    for (int mi = 0; mi < 4; mi++) {
        int mrow0 = m0 + wm + mi * 16 + quad * 4;
        int4 mk4 = {0, 0, 0, 0};
        if (MODE == 2 || MODE == 3) mk4 = *(const int4*)&mask[mrow0];
#pragma unroll
        for (int ni = 0; ni < NI; ni++) {
            int n = n0 + wn + ni * 16 + l16;
            float bv = bias[n];
            float vals[4];
#pragma unroll
            for (int reg = 0; reg < 4; reg++) vals[reg] = acc[mi][ni][reg] + bv;
            if (MODE == 0) {
                int nl = n - seg * DIM;
                if (seg == 2) {
                    int hh = nl / HD, d = nl - hh * HD;
                    int bb = mrow0 / NN, nb = mrow0 - bb * NN;
                    int T = nb >> 6, ko = nb & 63;
                    int c16 = ko & 15, kb = ko >> 4;
                    short* vp = o2 + ((size_t)((bb * HEADS + hh) * HD + d)) * NN + T * 64 + kb;
#pragma unroll
                    for (int reg = 0; reg < 4; reg++) vp[4 * (c16 + reg)] = f2bf(vals[reg]);
                } else {
                    short* dstq = (seg == 0) ? o0 : o1;
                    int pc = nl % HD;
#pragma unroll
                    for (int reg = 0; reg < 4; reg++) {
                        int m = mrow0 + reg;
                        float val = vals[reg];
                        if (seg == 1) val += pe[(size_t)m * HD + pc];
                        dstq[(size_t)m * DIM + nl] = f2bf(val);
                    }
                }
            } else if (MODE == 1) {
#pragma unroll
                for (int reg = 0; reg < 4; reg++)
                    o0[(size_t)(mrow0 + reg) * N + n] = f2bf(gelu_exact(vals[reg]));
            } else if (MODE == 2) {
#pragma unroll
                for (int reg = 0; reg < 4; reg++) {
                    int m = mrow0 + reg;
                    int mk = ((const int*)&mk4)[reg];
                    of[(size_t)m * N + n] = res[(size_t)m * N + n] + (mk ? vals[reg] : 0.f);
                }
            } else {
#pragma unroll
                for (int reg = 0; reg < 4; reg++) {
                    int m = mrow0 + reg;
                    int mk = ((const int*)&mk4)[reg];
                    of[(size_t)m * N + n] = mk ? (res[(size_t)m * N + n] + vals[reg]) : 0.f;
                }
            }
        }
    }
}

// ---------------- MFMA flash attention v7: single-barrier double-buffered ----------------
// 128-query blocks, 4 waves x 32 queries. K/V/mask LDS double-buffered; ONE barrier
// per tile (at end). QK frag reads issue right after the barrier; staging ds_writes
// (tile kt+1, regs prefetched in kt-1) + global loads (tile kt+2 -> regs) overlap the
// MFMA/softmax compute. vmcnt waits attach to register USE next iteration, so global
// loads stay in flight across the barrier. __expf + integer bf16 packing cut softmax
// VALU. XOR-swizzled K/V (conflict-free); packed-P key relabeling (V^T pre-permuted).
__global__ __launch_bounds__(256) void attn7_kernel(const short* __restrict__ q,
                                                    const short* __restrict__ k,
                                                    const short* __restrict__ vt,
                                                    const int* __restrict__ mask,
                                                    short* __restrict__ out) {
    const int b = blockIdx.z, h = blockIdx.y;
    const int q0 = blockIdx.x * 128;
    const int t = threadIdx.x;
    const int lane = t & 63;
    const int w = t >> 6;
    const int l16 = lane & 15;
    const int quad = lane >> 4;

    // LDS (shorts): KS0 @0, KS1 @4096 (64x64 each, swizzled); VT0 @8192, VT1 @11264
    // (48x64 each, swizzled); PL @14336 (4 waves x 32q x 72). 47104 B.
    __shared__ __align__(16) short SH[23552];
    __shared__ float madd2[2][64];

    // one-time zero chunks (K dims 48..63) for BOTH buffers: slots {6,7}^(r&7) are
    // disjoint from data slots {0..5}^(r&7), never overwritten by staging.
    {
        int buf = t >> 7, r = (t >> 1) & 63, zc = 6 + (t & 1);
        shortx8 z = {0, 0, 0, 0, 0, 0, 0, 0};
        *(shortx8*)&SH[buf * 4096 + r * 64 + ((zc ^ (r & 7)) * 8)] = z;
    }

    // staging plan: 768 chunk tasks (K 384 + V 384), 3/thread, loop-invariant
    const size_t vtbase = (size_t)((b * HEADS + h) * HD) * NN;
    const short* gsrc[3]; int loff[3]; int gstep[3]; int bstr[3];
#pragma unroll
    for (int i = 0; i < 3; i++) {
        int u = t + i * 256;
        if (u < 384) {
            int r = u / 6, c = u - r * 6;
            gsrc[i] = k + ((size_t)(b * NN + r)) * DIM + h * HD + c * 8;
            gstep[i] = 64 * DIM;
            loff[i] = r * 64 + ((c ^ (r & 7)) * 8);
            bstr[i] = 4096;
        } else {
            int uu = u - 384;
            int d = uu >> 3, ck = uu & 7;
            gsrc[i] = vt + vtbase + (size_t)d * NN + ck * 8;
            gstep[i] = 64;
            loff[i] = 8192 + d * 64 + ((ck ^ (d & 7)) * 8);
            bstr[i] = 3072;
        }
    }

    // prologue: tile0 -> buf0; tile1 -> regs
    shortx8 pre[3];
#pragma unroll
    for (int i = 0; i < 3; i++) pre[i] = *(const shortx8*)gsrc[i];
#pragma unroll
    for (int i = 0; i < 3; i++) *(shortx8*)&SH[loff[i]] = pre[i];
    if (t < 64) madd2[0][t] = mask[b * NN + t] ? 0.f : -1e30f;
#pragma unroll
    for (int i = 0; i < 3; i++) { gsrc[i] += gstep[i]; pre[i] = *(const shortx8*)gsrc[i]; }
    int mreg = (t < 64) ? mask[b * NN + 64 + t] : 0;

    // Q A-fragments (wave owns queries q0+w*32 .. +32)
    shortx8 qf[2][2];
#pragma unroll
    for (int mt = 0; mt < 2; mt++) {
        const short* qp = q + ((size_t)(b * NN + q0 + w * 32 + mt * 16 + l16)) * DIM + h * HD;
        qf[mt][0] = *(const shortx8*)&qp[quad * 8];
        if (quad < 2) qf[mt][1] = *(const shortx8*)&qp[32 + quad * 8];
        else          qf[mt][1] = (shortx8){0, 0, 0, 0, 0, 0, 0, 0};
    }

    floatx4 acc[2][3] = {};
    float lsum[2][4] = {};
    const float cs = 0.14433756729740643f;  // 1/sqrt(48); __expf handles log2(e)
    const int plb = 14336 + w * 2304;
    const int sw = (l16 & 7);

    __syncthreads();

    for (int kt = 0; kt < 32; kt++) {
        const int cur = kt & 1, nxt = cur ^ 1;
        const int kso = cur * 4096, vto = 8192 + cur * 3072;

        // QK frag reads first (cur buffer ready per barrier)
        shortx8 kb[4][2];
#pragma unroll
        for (int nt = 0; nt < 4; nt++) {
            int r = nt * 16 + l16;
            kb[nt][0] = *(const shortx8*)&SH[kso + r * 64 + ((quad ^ sw) * 8)];
            kb[nt][1] = *(const shortx8*)&SH[kso + r * 64 + (((4 + quad) ^ sw) * 8)];
        }
        // stage tile kt+1 into nxt buffers; launch loads for tile kt+2
        if (kt < 31) {
#pragma unroll
            for (int i = 0; i < 3; i++) *(shortx8*)&SH[loff[i] + nxt * bstr[i]] = pre[i];
            if (t < 64) madd2[nxt][t] = mreg ? 0.f : -1e30f;
            if (kt < 30) {
#pragma unroll
                for (int i = 0; i < 3; i++) { gsrc[i] += gstep[i]; pre[i] = *(const shortx8*)gsrc[i]; }
                if (t < 64) mreg = mask[b * NN + (kt + 2) * 64 + t];
            }
        }

        // QK^T
        floatx4 S[2][4];
#pragma unroll
        for (int nt = 0; nt < 4; nt++)
#pragma unroll
            for (int mt = 0; mt < 2; mt++) {
                floatx4 s = {0.f, 0.f, 0.f, 0.f};
                s = __builtin_amdgcn_mfma_f32_16x16x32_bf16(qf[mt][0], kb[nt][0], s, 0, 0, 0);
                s = __builtin_amdgcn_mfma_f32_16x16x32_bf16(qf[mt][1], kb[nt][1], s, 0, 0, 0);
                S[mt][nt] = s;
            }
        // softmax-lite + packed P store (cols key_new = 4*l16+nt)
#pragma unroll
        for (int mt = 0; mt < 2; mt++) {
            float p[4][4];
#pragma unroll
            for (int nt = 0; nt < 4; nt++) {
                float ad = madd2[cur][nt * 16 + l16];
#pragma unroll
                for (int reg = 0; reg < 4; reg++) {
                    float pv = __expf(S[mt][nt][reg] * cs + ad);
                    p[nt][reg] = pv;
                    lsum[mt][reg] += pv;
                }
            }
#pragma unroll
            for (int reg = 0; reg < 4; reg++) {
                *(uint2*)&SH[plb + (mt * 16 + quad * 4 + reg) * 72 + l16 * 4] =
                    make_uint2(pkbf(p[0][reg], p[1][reg]), pkbf(p[2][reg], p[3][reg]));
            }
        }
        // PV over key_new axis (V^T pre-permuted)
#pragma unroll
        for (int c = 0; c < 2; c++) {
            shortx8 pf[2];
#pragma unroll
            for (int mt = 0; mt < 2; mt++)
                pf[mt] = *(const shortx8*)&SH[plb + (mt * 16 + l16) * 72 + c * 32 + quad * 8];
#pragma unroll
            for (int dt = 0; dt < 3; dt++) {
                shortx8 vf = *(const shortx8*)&SH[vto + (dt * 16 + l16) * 64 + (((c * 4 + quad) ^ sw) * 8)];
#pragma unroll
                for (int mt = 0; mt < 2; mt++)
                    acc[mt][dt] = __builtin_amdgcn_mfma_f32_16x16x32_bf16(pf[mt], vf, acc[mt][dt], 0, 0, 0);
            }
        }
        __syncthreads();  // staged writes visible; all waves done with cur
    }

    // final: reduce l across the 16 key-columns, scale, store bf16
#pragma unroll
    for (int mt = 0; mt < 2; mt++)
#pragma unroll
        for (int reg = 0; reg < 4; reg++) {
            float s = lsum[mt][reg];
#pragma unroll
            for (int off = 1; off < 16; off <<= 1) s += __shfl_xor(s, off, 64);
            lsum[mt][reg] = 1.f / s;
        }
#pragma unroll
    for (int mt = 0; mt < 2; mt++)
#pragma unroll
        for (int dt = 0; dt < 3; dt++)
#pragma unroll
            for (int reg = 0; reg < 4; reg++) {
                size_t row = (size_t)(b * NN + q0 + w * 32 + mt * 16 + quad * 4 + reg);
                out[row * DIM + h * HD + dt * 16 + l16] = f2bf_c(acc[mt][dt][reg] * lsum[mt][reg]);
            }
}

extern "C" void kernel_launch(void* const* d_in, const int* in_sizes, int n_in,
                              void* d_out, int out_size, void* d_ws, size_t ws_size,
                              hipStream_t stream) {
    const float* x   = (const float*)d_in[0];
    const float* pos = (const float*)d_in[1];
    const int*   mask= (const int*)  d_in[2];
    const float* Wq  = (const float*)d_in[3];
    const float* bq  = (const float*)d_in[4];
    const float* Wk  = (const float*)d_in[5];
    const float* bk  = (const float*)d_in[6];
    const float* Wv  = (const float*)d_in[7];
    const float* bv  = (const float*)d_in[8];
    const float* pw1 = (const float*)d_in[9];
    const float* pb1 = (const float*)d_in[10];
    const float* pw2 = (const float*)d_in[11];
    const float* pb2 = (const float*)d_in[12];
    const float* Wo  = (const float*)d_in[13];
    const float* bo  = (const float*)d_in[14];
    const float* mw1 = (const float*)d_in[15];
    const float* mb1 = (const float*)d_in[16];
    const float* mw2 = (const float*)d_in[17];
    const float* mb2 = (const float*)d_in[18];
    const float* g1  = (const float*)d_in[19];
    const float* be1 = (const float*)d_in[20];
    const float* g2  = (const float*)d_in[21];
    const float* be2 = (const float*)d_in[22];
    float* out = (float*)d_out;

    // workspace layout (bytes)
    char* wsb = (char*)d_ws;
    short* h_bf    = (short*)(wsb + 0);           // 6291456
    short* q_bf    = (short*)(wsb + 6291456);
    short* k_bf    = (short*)(wsb + 12582912);
    short* vt_bf   = (short*)(wsb + 18874368);    // V^T [b][h][d][n], key-permuted
    short* attn_bf = (short*)(wsb + 25165824);
    short* mlph_bf = h_bf;                        // overlays h|q|k|vt (dead by MLP1)
    float* pebuf   = (float*)(wsb + 31457280);    // 1572864
    float* x1      = (float*)(wsb + 33030144);    // 12582912
    short* h2_bf   = (short*)(wsb + 45613056);    // 6291456
    short* Wqkv_t  = (short*)(wsb + 51904512);    // [1152][384] bf16
    short* Wo_t    = (short*)(wsb + 52789248);    // [384][384]
    short* mw1_t   = (short*)(wsb + 53084160);    // [1536][384]
    short* mw2_t   = (short*)(wsb + 54263808);    // [384][1536]
    float* bqkv    = (float*)(wsb + 55443456);    // [1152]

    // --- fused head: weight prep + LN1 + pos-MLP (1 launch) ---
    head_kernel<<<5825, 256, 0, stream>>>(Wq, Wk, Wv, Wo, mw1, mw2, bq, bk, bv,
                                          x, g1, be1, pos, pw1, pb1, pw2, pb2,
                                          Wqkv_t, Wo_t, mw1_t, mw2_t, bqkv, h_bf, pebuf);

    // fused QKV: [8192,1152] = h @ [Wq|Wk|Wv]; epilogue: q/k row-major (+pe on k), V^T permuted
    gemm3_kernel<0, 128><<<dim3(3 * DIM / 128, ROWS / 128), 256, 0, stream>>>(
        h_bf, Wqkv_t, bqkv, pebuf, nullptr, nullptr, nullptr, q_bf, k_bf, vt_bf,
        ROWS, 3 * DIM, DIM);

    // attention: 512 blocks of 128 queries, single-barrier dbuf pipeline
    attn7_kernel<<<dim3(NN / 128, HEADS, BB), 256, 0, stream>>>(
        q_bf, k_bf, vt_bf, mask, attn_bf);

    // Wo + residual + mask -> x1 fp32
    gemm3_kernel<2, 128><<<dim3(DIM / 128, ROWS / 128), 256, 0, stream>>>(
        attn_bf, Wo_t, bo, nullptr, x, mask, x1, nullptr, nullptr, nullptr,
        ROWS, DIM, DIM);

    ln_bf16_kernel<<<ROWS / 4, 256, 0, stream>>>(x1, g2, be2, h2_bf);

    // MLP1 (exact gelu) -> bf16 hidden
    gemm3_kernel<1, 128><<<dim3(MLPH / 128, ROWS / 128), 256, 0, stream>>>(
        h2_bf, mw1_t, mb1, nullptr, nullptr, nullptr, nullptr, mlph_bf, nullptr, nullptr,
        ROWS, MLPH, DIM);

    // MLP2 + residual + mask -> out fp32
    gemm3_kernel<3, 128><<<dim3(DIM / 128, ROWS / 128), 256, 0, stream>>>(
        mlph_bf, mw2_t, mb2, nullptr, x1, mask, out, nullptr, nullptr, nullptr,
        ROWS, DIM, MLPH);
}

// Round 10
// 262.999 us; speedup vs baseline: 1.1523x; 1.0852x over previous
//
#include <hip/hip_runtime.h>
#include <hip/hip_bf16.h>
#include <math.h>

// Problem constants
#define BB 4
#define NN 2048
#define DIM 384
#define HEADS 8
#define HD 48
#define MLPH 1536
#define ROWS (BB*NN)          // 8192
#define SZ ((size_t)ROWS*DIM) // 3145728 elems per (B,N,DIM) buffer

typedef float floatx4 __attribute__((ext_vector_type(4)));
typedef short shortx8 __attribute__((ext_vector_type(8)));

__device__ __forceinline__ float gelu_exact(float x) {
    return 0.5f * x * (1.0f + erff(x * 0.70710678118654752f));
}

__device__ __forceinline__ short f2bf(float f) {
    __hip_bfloat16 h = __float2bfloat16(f);
    return *reinterpret_cast<short*>(&h);
}

// cheap bf16 pack: round-half-up on positive values (p = exp(..) >= 0)
__device__ __forceinline__ unsigned pkbf(float a, float b) {
    return ((__float_as_uint(a) + 0x8000u) >> 16) |
           ((__float_as_uint(b) + 0x8000u) & 0xFFFF0000u);
}
__device__ __forceinline__ short f2bf_c(float f) {
    return (short)((__float_as_uint(f) + 0x8000u) >> 16);
}

// ---------------- LayerNorm: 4 rows/block (one wave each), fp32 -> bf16 ----------------
__global__ __launch_bounds__(256) void ln_bf16_kernel(const float* __restrict__ x,
                                                      const float* __restrict__ g,
                                                      const float* __restrict__ be,
                                                      short* __restrict__ out) {
    int row = blockIdx.x * 4 + (threadIdx.x >> 6);
    int lane = threadIdx.x & 63;
    const float* xp = x + (size_t)row * DIM;
    float v[6];
    float sum = 0.f, sumsq = 0.f;
#pragma unroll
    for (int j = 0; j < 6; j++) {
        float val = xp[lane + j * 64];
        v[j] = val; sum += val; sumsq += val * val;
    }
#pragma unroll
    for (int off = 1; off < 64; off <<= 1) {
        sum += __shfl_xor(sum, off, 64);
        sumsq += __shfl_xor(sumsq, off, 64);
    }
    float mean = sum * (1.f / DIM);
    float var = sumsq * (1.f / DIM) - mean * mean;
    float rstd = rsqrtf(var + 1e-5f);
    short* op = out + (size_t)row * DIM;
#pragma unroll
    for (int j = 0; j < 6; j++) {
        int c = lane + j * 64;
        op[c] = f2bf((v[j] - mean) * rstd * g[c] + be[c]);
    }
}

// ---------------- fused head: weight transposes + bias concat + LN1 + pos-MLP ----------
__global__ __launch_bounds__(256) void head_kernel(const float* __restrict__ Wq,
                                                   const float* __restrict__ Wk,
                                                   const float* __restrict__ Wv,
                                                   const float* __restrict__ Wo,
                                                   const float* __restrict__ mw1,
                                                   const float* __restrict__ mw2,
                                                   const float* __restrict__ bq,
                                                   const float* __restrict__ bk,
                                                   const float* __restrict__ bv,
                                                   const float* __restrict__ x,
                                                   const float* __restrict__ g1,
                                                   const float* __restrict__ be1,
                                                   const float* __restrict__ pos,
                                                   const float* __restrict__ pw1,
                                                   const float* __restrict__ pb1,
                                                   const float* __restrict__ pw2,
                                                   const float* __restrict__ pb2,
                                                   short* __restrict__ Wqkv_t,
                                                   short* __restrict__ Wo_t,
                                                   short* __restrict__ mw1_t,
                                                   short* __restrict__ mw2_t,
                                                   float* __restrict__ bqkv,
                                                   short* __restrict__ h_bf,
                                                   float* __restrict__ pe) {
    __shared__ float tile[32][33];
    __shared__ float pw2s[HD * HD];
    __shared__ float hsh[4][HD];
    const int id = blockIdx.x;
    const int t = threadIdx.x;
    if (id < 1728) {
        const float* src; short* dst; int K, N, tid;
        if (id < 144)       { src = Wq;  dst = Wqkv_t;          K = 384;  N = 384;  tid = id; }
        else if (id < 288)  { src = Wk;  dst = Wqkv_t + 147456; K = 384;  N = 384;  tid = id - 144; }
        else if (id < 432)  { src = Wv;  dst = Wqkv_t + 294912; K = 384;  N = 384;  tid = id - 288; }
        else if (id < 576)  { src = Wo;  dst = Wo_t;            K = 384;  N = 384;  tid = id - 432; }
        else if (id < 1152) { src = mw1; dst = mw1_t;           K = 384;  N = 1536; tid = id - 576; }
        else                { src = mw2; dst = mw2_t;           K = 1536; N = 384;  tid = id - 1152; }
        int ntx = N / 32;
        int n0 = (tid % ntx) * 32, k0 = (tid / ntx) * 32;
        int c = t & 31, r4 = t >> 5;
#pragma unroll
        for (int i = 0; i < 4; i++) {
            int r = r4 + i * 8;
            tile[r][c] = src[(size_t)(k0 + r) * N + n0 + c];
        }
        __syncthreads();
#pragma unroll
        for (int i = 0; i < 4; i++) {
            int r = r4 + i * 8;
            dst[(size_t)(n0 + r) * K + k0 + c] = f2bf(tile[c][r]);
        }
    } else if (id == 1728) {
        for (int i = t; i < 3 * DIM; i += 256)
            bqkv[i] = i < DIM ? bq[i] : (i < 2 * DIM ? bk[i - DIM] : bv[i - 2 * DIM]);
    } else if (id < 3777) {
        int row = (id - 1729) * 4 + (t >> 6);
        int lane = t & 63;
        const float* xp = x + (size_t)row * DIM;
        float v[6];
        float sum = 0.f, sumsq = 0.f;
#pragma unroll
        for (int j = 0; j < 6; j++) {
            float val = xp[lane + j * 64];
            v[j] = val; sum += val; sumsq += val * val;
        }
#pragma unroll
        for (int off = 1; off < 64; off <<= 1) {
            sum += __shfl_xor(sum, off, 64);
            sumsq += __shfl_xor(sumsq, off, 64);
        }
        float mean = sum * (1.f / DIM);
        float var = sumsq * (1.f / DIM) - mean * mean;
        float rstd = rsqrtf(var + 1e-5f);
        short* op = h_bf + (size_t)row * DIM;
#pragma unroll
        for (int j = 0; j < 6; j++) {
            int c = lane + j * 64;
            op[c] = f2bf((v[j] - mean) * rstd * g1[c] + be1[c]);
        }
    } else {
        int w = t >> 6, lane = t & 63;
        int p = (id - 3777) * 4 + w;
        for (int i = t; i < HD * HD; i += 256) pw2s[i] = pw2[i];
        float px = pos[(size_t)p * 3 + 0];
        float py = pos[(size_t)p * 3 + 1];
        float pz = pos[(size_t)p * 3 + 2];
        __syncthreads();
        if (lane < HD) {
            float hv = px * pw1[0 * HD + lane] + py * pw1[1 * HD + lane] + pz * pw1[2 * HD + lane] + pb1[lane];
            hsh[w][lane] = gelu_exact(hv);
        }
        if (lane < HD) {
            float o = pb2[lane];
#pragma unroll 8
            for (int i = 0; i < HD; i++) o += hsh[w][i] * pw2s[i * HD + lane];
            pe[(size_t)p * HD + lane] = o;
        }
    }
}

// ---------------- bf16 MFMA GEMM v4: C[M,N] = A[M,K] @ Bt[N,K]^T + bias ----------------
// TM x 128 tile, BK=64. TM=128: 4 waves 2x2 (acc 64 VGPR). TM=64: 4 waves 1x4 along N
// (acc 32 VGPR, LDS 24 KB -> lighter blocks, 2x grid for parallelism-starved GEMMs).
// XOR-8 swizzle + 1-tile register prefetch. Pure-DS two-barrier staging.
// MODE 0: QKV fused -> q/k row-major bf16 (pe added to k), V^T permuted (key_new =
//         4*(key%16)+key/16 per 64-key tile, matching attention's packed-P layout).
// MODE 1: exact gelu -> bf16 (MLP1)
// MODE 2: of = res + (mask ? v : 0)  fp32 (Wo + residual)
// MODE 3: of = mask ? (res + v) : 0  fp32 (MLP2 + residual + mask)
template <int MODE, int TM>
__global__ __launch_bounds__(256) void gemm4_kernel(const short* __restrict__ A,
                                                    const short* __restrict__ Bt,
                                                    const float* __restrict__ bias,
                                                    const float* __restrict__ pe,
                                                    const float* __restrict__ res,
                                                    const int* __restrict__ mask,
                                                    float* __restrict__ of,
                                                    short* __restrict__ o0,
                                                    short* __restrict__ o1,
                                                    short* __restrict__ o2,
                                                    int M, int N, int K) {
    constexpr int QA = TM / 32;                  // A staging chunks per thread
    constexpr int NI = (TM == 128) ? 4 : 2;      // B-frag tiles per wave
    __shared__ short As[TM * 64];
    __shared__ short Bs[128 * 64];
    const int t = threadIdx.x, lane = t & 63, w = t >> 6;
    const int l16 = lane & 15, quad = lane >> 4;
    const int m0 = blockIdx.y * TM, n0 = blockIdx.x * 128;
    const int wm = (TM == 128) ? (w & 1) * 64 : 0;
    const int wn = (TM == 128) ? (w >> 1) * 64 : w * 32;

    const int rr = t >> 3, gc = t & 7, cshort = gc * 8;
    const short* gA[QA]; int ldsoA[QA];
    const short* gB[4];  int ldsoB[4];
#pragma unroll
    for (int qc = 0; qc < QA; qc++) {
        int r = qc * 32 + rr;
        gA[qc] = A + (size_t)(m0 + r) * K + cshort;
        ldsoA[qc] = r * 64 + ((gc ^ (r & 7)) * 8);
    }
#pragma unroll
    for (int qc = 0; qc < 4; qc++) {
        int r = qc * 32 + rr;
        gB[qc] = Bt + (size_t)(n0 + r) * K + cshort;
        ldsoB[qc] = r * 64 + ((gc ^ (r & 7)) * 8);
    }

    floatx4 acc[4][NI] = {};
    const int sA = l16 & 7;

    shortx8 ra[QA], rb[4];
#pragma unroll
    for (int qc = 0; qc < QA; qc++) ra[qc] = *(const shortx8*)gA[qc];
#pragma unroll
    for (int qc = 0; qc < 4; qc++) rb[qc] = *(const shortx8*)gB[qc];

    for (int k0 = 0; k0 < K; k0 += 64) {
        __syncthreads();
#pragma unroll
        for (int qc = 0; qc < QA; qc++) *(shortx8*)&As[ldsoA[qc]] = ra[qc];
#pragma unroll
        for (int qc = 0; qc < 4; qc++) *(shortx8*)&Bs[ldsoB[qc]] = rb[qc];
        __syncthreads();
        if (k0 + 64 < K) {
#pragma unroll
            for (int qc = 0; qc < QA; qc++) ra[qc] = *(const shortx8*)(gA[qc] + k0 + 64);
#pragma unroll
            for (int qc = 0; qc < 4; qc++) rb[qc] = *(const shortx8*)(gB[qc] + k0 + 64);
        }
#pragma unroll
        for (int kkc = 0; kkc < 2; kkc++) {
            shortx8 af[4], bfr[NI];
            int slot = ((quad + kkc * 4) ^ sA) * 8;
#pragma unroll
            for (int i = 0; i < 4; i++)
                af[i] = *(const shortx8*)&As[(wm + i * 16 + l16) * 64 + slot];
#pragma unroll
            for (int i = 0; i < NI; i++)
                bfr[i] = *(const shortx8*)&Bs[(wn + i * 16 + l16) * 64 + slot];
#pragma unroll
            for (int mi = 0; mi < 4; mi++)
#pragma unroll
                for (int ni = 0; ni < NI; ni++)
                    acc[mi][ni] = __builtin_amdgcn_mfma_f32_16x16x32_bf16(af[mi], bfr[ni], acc[mi][ni], 0, 0, 0);
        }
    }

    const int seg = (MODE == 0) ? (n0 / DIM) : 0;
#pragma unroll
    for (int mi = 0; mi < 4; mi++) {
        int mrow0 = m0 + wm + mi * 16 + quad * 4;
        int4 mk4 = {0, 0, 0, 0};
        if (MODE == 2 || MODE == 3) mk4 = *(const int4*)&mask[mrow0];
#pragma unroll
        for (int ni = 0; ni < NI; ni++) {
            int n = n0 + wn + ni * 16 + l16;
            float bv = bias[n];
            float vals[4];
#pragma unroll
            for (int reg = 0; reg < 4; reg++) vals[reg] = acc[mi][ni][reg] + bv;
            if (MODE == 0) {
                int nl = n - seg * DIM;
                if (seg == 2) {
                    int hh = nl / HD, d = nl - hh * HD;
                    int bb = mrow0 / NN, nb = mrow0 - bb * NN;
                    int T = nb >> 6, ko = nb & 63;
                    int c16 = ko & 15, kb = ko >> 4;
                    short* vp = o2 + ((size_t)((bb * HEADS + hh) * HD + d)) * NN + T * 64 + kb;
#pragma unroll
                    for (int reg = 0; reg < 4; reg++) vp[4 * (c16 + reg)] = f2bf(vals[reg]);
                } else {
                    short* dstq = (seg == 0) ? o0 : o1;
                    int pc = nl % HD;
#pragma unroll
                    for (int reg = 0; reg < 4; reg++) {
                        int m = mrow0 + reg;
                        float val = vals[reg];
                        if (seg == 1) val += pe[(size_t)m * HD + pc];
                        dstq[(size_t)m * DIM + nl] = f2bf(val);
                    }
                }
            } else if (MODE == 1) {
#pragma unroll
                for (int reg = 0; reg < 4; reg++)
                    o0[(size_t)(mrow0 + reg) * N + n] = f2bf(gelu_exact(vals[reg]));
            } else if (MODE == 2) {
#pragma unroll
                for (int reg = 0; reg < 4; reg++) {
                    int m = mrow0 + reg;
                    int mk = ((const int*)&mk4)[reg];
                    of[(size_t)m * N + n] = res[(size_t)m * N + n] + (mk ? vals[reg] : 0.f);
                }
            } else {
#pragma unroll
                for (int reg = 0; reg < 4; reg++) {
                    int m = mrow0 + reg;
                    int mk = ((const int*)&mk4)[reg];
                    of[(size_t)m * N + n] = mk ? (res[(size_t)m * N + n] + vals[reg]) : 0.f;
                }
            }
        }
    }
}

// ---------------- MFMA flash attention v7: single-barrier double-buffered ----------------
__global__ __launch_bounds__(256) void attn7_kernel(const short* __restrict__ q,
                                                    const short* __restrict__ k,
                                                    const short* __restrict__ vt,
                                                    const int* __restrict__ mask,
                                                    short* __restrict__ out) {
    const int b = blockIdx.z, h = blockIdx.y;
    const int q0 = blockIdx.x * 128;
    const int t = threadIdx.x;
    const int lane = t & 63;
    const int w = t >> 6;
    const int l16 = lane & 15;
    const int quad = lane >> 4;

    __shared__ __align__(16) short SH[23552];
    __shared__ float madd2[2][64];

    {
        int buf = t >> 7, r = (t >> 1) & 63, zc = 6 + (t & 1);
        shortx8 z = {0, 0, 0, 0, 0, 0, 0, 0};
        *(shortx8*)&SH[buf * 4096 + r * 64 + ((zc ^ (r & 7)) * 8)] = z;
    }

    const size_t vtbase = (size_t)((b * HEADS + h) * HD) * NN;
    const short* gsrc[3]; int loff[3]; int gstep[3]; int bstr[3];
#pragma unroll
    for (int i = 0; i < 3; i++) {
        int u = t + i * 256;
        if (u < 384) {
            int r = u / 6, c = u - r * 6;
            gsrc[i] = k + ((size_t)(b * NN + r)) * DIM + h * HD + c * 8;
            gstep[i] = 64 * DIM;
            loff[i] = r * 64 + ((c ^ (r & 7)) * 8);
            bstr[i] = 4096;
        } else {
            int uu = u - 384;
            int d = uu >> 3, ck = uu & 7;
            gsrc[i] = vt + vtbase + (size_t)d * NN + ck * 8;
            gstep[i] = 64;
            loff[i] = 8192 + d * 64 + ((ck ^ (d & 7)) * 8);
            bstr[i] = 3072;
        }
    }

    shortx8 pre[3];
#pragma unroll
    for (int i = 0; i < 3; i++) pre[i] = *(const shortx8*)gsrc[i];
#pragma unroll
    for (int i = 0; i < 3; i++) *(shortx8*)&SH[loff[i]] = pre[i];
    if (t < 64) madd2[0][t] = mask[b * NN + t] ? 0.f : -1e30f;
#pragma unroll
    for (int i = 0; i < 3; i++) { gsrc[i] += gstep[i]; pre[i] = *(const shortx8*)gsrc[i]; }
    int mreg = (t < 64) ? mask[b * NN + 64 + t] : 0;

    shortx8 qf[2][2];
#pragma unroll
    for (int mt = 0; mt < 2; mt++) {
        const short* qp = q + ((size_t)(b * NN + q0 + w * 32 + mt * 16 + l16)) * DIM + h * HD;
        qf[mt][0] = *(const shortx8*)&qp[quad * 8];
        if (quad < 2) qf[mt][1] = *(const shortx8*)&qp[32 + quad * 8];
        else          qf[mt][1] = (shortx8){0, 0, 0, 0, 0, 0, 0, 0};
    }

    floatx4 acc[2][3] = {};
    float lsum[2][4] = {};
    const float cs = 0.14433756729740643f;
    const int plb = 14336 + w * 2304;
    const int sw = (l16 & 7);

    __syncthreads();

    for (int kt = 0; kt < 32; kt++) {
        const int cur = kt & 1, nxt = cur ^ 1;
        const int kso = cur * 4096, vto = 8192 + cur * 3072;

        shortx8 kb[4][2];
#pragma unroll
        for (int nt = 0; nt < 4; nt++) {
            int r = nt * 16 + l16;
            kb[nt][0] = *(const shortx8*)&SH[kso + r * 64 + ((quad ^ sw) * 8)];
            kb[nt][1] = *(const shortx8*)&SH[kso + r * 64 + (((4 + quad) ^ sw) * 8)];
        }
        if (kt < 31) {
#pragma unroll
            for (int i = 0; i < 3; i++) *(shortx8*)&SH[loff[i] + nxt * bstr[i]] = pre[i];
            if (t < 64) madd2[nxt][t] = mreg ? 0.f : -1e30f;
            if (kt < 30) {
#pragma unroll
                for (int i = 0; i < 3; i++) { gsrc[i] += gstep[i]; pre[i] = *(const shortx8*)gsrc[i]; }
                if (t < 64) mreg = mask[b * NN + (kt + 2) * 64 + t];
            }
        }

        floatx4 S[2][4];
#pragma unroll
        for (int nt = 0; nt < 4; nt++)
#pragma unroll
            for (int mt = 0; mt < 2; mt++) {
                floatx4 s = {0.f, 0.f, 0.f, 0.f};
                s = __builtin_amdgcn_mfma_f32_16x16x32_bf16(qf[mt][0], kb[nt][0], s, 0, 0, 0);
                s = __builtin_amdgcn_mfma_f32_16x16x32_bf16(qf[mt][1], kb[nt][1], s, 0, 0, 0);
                S[mt][nt] = s;
            }
#pragma unroll
        for (int mt = 0; mt < 2; mt++) {
            float p[4][4];
#pragma unroll
            for (int nt = 0; nt < 4; nt++) {
                float ad = madd2[cur][nt * 16 + l16];
#pragma unroll
                for (int reg = 0; reg < 4; reg++) {
                    float pv = __expf(S[mt][nt][reg] * cs + ad);
                    p[nt][reg] = pv;
                    lsum[mt][reg] += pv;
                }
            }
#pragma unroll
            for (int reg = 0; reg < 4; reg++) {
                *(uint2*)&SH[plb + (mt * 16 + quad * 4 + reg) * 72 + l16 * 4] =
                    make_uint2(pkbf(p[0][reg], p[1][reg]), pkbf(p[2][reg], p[3][reg]));
            }
        }
#pragma unroll
        for (int c = 0; c < 2; c++) {
            shortx8 pf[2];
#pragma unroll
            for (int mt = 0; mt < 2; mt++)
                pf[mt] = *(const shortx8*)&SH[plb + (mt * 16 + l16) * 72 + c * 32 + quad * 8];
#pragma unroll
            for (int dt = 0; dt < 3; dt++) {
                shortx8 vf = *(const shortx8*)&SH[vto + (dt * 16 + l16) * 64 + (((c * 4 + quad) ^ sw) * 8)];
#pragma unroll
                for (int mt = 0; mt < 2; mt++)
                    acc[mt][dt] = __builtin_amdgcn_mfma_f32_16x16x32_bf16(pf[mt], vf, acc[mt][dt], 0, 0, 0);
            }
        }
        __syncthreads();
    }

#pragma unroll
    for (int mt = 0; mt < 2; mt++)
#pragma unroll
        for (int reg = 0; reg < 4; reg++) {
            float s = lsum[mt][reg];
#pragma unroll
            for (int off = 1; off < 16; off <<= 1) s += __shfl_xor(s, off, 64);
            lsum[mt][reg] = 1.f / s;
        }
#pragma unroll
    for (int mt = 0; mt < 2; mt++)
#pragma unroll
        for (int dt = 0; dt < 3; dt++)
#pragma unroll
            for (int reg = 0; reg < 4; reg++) {
                size_t row = (size_t)(b * NN + q0 + w * 32 + mt * 16 + quad * 4 + reg);
                out[row * DIM + h * HD + dt * 16 + l16] = f2bf_c(acc[mt][dt][reg] * lsum[mt][reg]);
            }
}

extern "C" void kernel_launch(void* const* d_in, const int* in_sizes, int n_in,
                              void* d_out, int out_size, void* d_ws, size_t ws_size,
                              hipStream_t stream) {
    const float* x   = (const float*)d_in[0];
    const float* pos = (const float*)d_in[1];
    const int*   mask= (const int*)  d_in[2];
    const float* Wq  = (const float*)d_in[3];
    const float* bq  = (const float*)d_in[4];
    const float* Wk  = (const float*)d_in[5];
    const float* bk  = (const float*)d_in[6];
    const float* Wv  = (const float*)d_in[7];
    const float* bv  = (const float*)d_in[8];
    const float* pw1 = (const float*)d_in[9];
    const float* pb1 = (const float*)d_in[10];
    const float* pw2 = (const float*)d_in[11];
    const float* pb2 = (const float*)d_in[12];
    const float* Wo  = (const float*)d_in[13];
    const float* bo  = (const float*)d_in[14];
    const float* mw1 = (const float*)d_in[15];
    const float* mb1 = (const float*)d_in[16];
    const float* mw2 = (const float*)d_in[17];
    const float* mb2 = (const float*)d_in[18];
    const float* g1  = (const float*)d_in[19];
    const float* be1 = (const float*)d_in[20];
    const float* g2  = (const float*)d_in[21];
    const float* be2 = (const float*)d_in[22];
    float* out = (float*)d_out;

    // workspace layout (bytes)
    char* wsb = (char*)d_ws;
    short* h_bf    = (short*)(wsb + 0);           // 6291456
    short* q_bf    = (short*)(wsb + 6291456);
    short* k_bf    = (short*)(wsb + 12582912);
    short* vt_bf   = (short*)(wsb + 18874368);    // V^T [b][h][d][n], key-permuted
    short* attn_bf = (short*)(wsb + 25165824);
    short* mlph_bf = h_bf;                        // overlays h|q|k|vt (dead by MLP1)
    float* pebuf   = (float*)(wsb + 31457280);    // 1572864
    float* x1      = (float*)(wsb + 33030144);    // 12582912
    short* h2_bf   = (short*)(wsb + 45613056);    // 6291456
    short* Wqkv_t  = (short*)(wsb + 51904512);    // [1152][384] bf16
    short* Wo_t    = (short*)(wsb + 52789248);    // [384][384]
    short* mw1_t   = (short*)(wsb + 53084160);    // [1536][384]
    short* mw2_t   = (short*)(wsb + 54263808);    // [384][1536]
    float* bqkv    = (float*)(wsb + 55443456);    // [1152]

    // --- fused head: weight prep + LN1 + pos-MLP (1 launch) ---
    head_kernel<<<5825, 256, 0, stream>>>(Wq, Wk, Wv, Wo, mw1, mw2, bq, bk, bv,
                                          x, g1, be1, pos, pw1, pb1, pw2, pb2,
                                          Wqkv_t, Wo_t, mw1_t, mw2_t, bqkv, h_bf, pebuf);

    // fused QKV: TM=64 -> 1152 blocks
    gemm4_kernel<0, 64><<<dim3(3 * DIM / 128, ROWS / 64), 256, 0, stream>>>(
        h_bf, Wqkv_t, bqkv, pebuf, nullptr, nullptr, nullptr, q_bf, k_bf, vt_bf,
        ROWS, 3 * DIM, DIM);

    // attention: 512 blocks of 128 queries, single-barrier dbuf pipeline
    attn7_kernel<<<dim3(NN / 128, HEADS, BB), 256, 0, stream>>>(
        q_bf, k_bf, vt_bf, mask, attn_bf);

    // Wo + residual + mask -> x1 fp32 (TM=64 -> 384 blocks)
    gemm4_kernel<2, 64><<<dim3(DIM / 128, ROWS / 64), 256, 0, stream>>>(
        attn_bf, Wo_t, bo, nullptr, x, mask, x1, nullptr, nullptr, nullptr,
        ROWS, DIM, DIM);

    ln_bf16_kernel<<<ROWS / 4, 256, 0, stream>>>(x1, g2, be2, h2_bf);

    // MLP1 (exact gelu) -> bf16 hidden (TM=64 -> 1536 blocks)
    gemm4_kernel<1, 64><<<dim3(MLPH / 128, ROWS / 64), 256, 0, stream>>>(
        h2_bf, mw1_t, mb1, nullptr, nullptr, nullptr, nullptr, mlph_bf, nullptr, nullptr,
        ROWS, MLPH, DIM);

    // MLP2 + residual + mask -> out fp32 (TM=64 -> 384 blocks)
    gemm4_kernel<3, 64><<<dim3(DIM / 128, ROWS / 64), 256, 0, stream>>>(
        mlph_bf, mw2_t, mb2, nullptr, x1, mask, out, nullptr, nullptr, nullptr,
        ROWS, DIM, MLPH);
}

// Round 11
// 261.389 us; speedup vs baseline: 1.1594x; 1.0062x over previous
//
#include <hip/hip_runtime.h>
#include <hip/hip_bf16.h>
#include <math.h>

// Problem constants
#define BB 4
#define NN 2048
#define DIM 384
#define HEADS 8
#define HD 48
#define MLPH 1536
#define ROWS (BB*NN)          // 8192
#define SZ ((size_t)ROWS*DIM) // 3145728 elems per (B,N,DIM) buffer

typedef float floatx4 __attribute__((ext_vector_type(4)));
typedef short shortx8 __attribute__((ext_vector_type(8)));

__device__ __forceinline__ float gelu_exact(float x) {
    return 0.5f * x * (1.0f + erff(x * 0.70710678118654752f));
}

__device__ __forceinline__ short f2bf(float f) {
    __hip_bfloat16 h = __float2bfloat16(f);
    return *reinterpret_cast<short*>(&h);
}

// cheap bf16 pack: round-half-up on positive values (p = exp(..) >= 0)
__device__ __forceinline__ unsigned pkbf(float a, float b) {
    return ((__float_as_uint(a) + 0x8000u) >> 16) |
           ((__float_as_uint(b) + 0x8000u) & 0xFFFF0000u);
}
__device__ __forceinline__ short f2bf_c(float f) {
    return (short)((__float_as_uint(f) + 0x8000u) >> 16);
}

// ---------------- LayerNorm: 4 rows/block (one wave each), fp32 -> bf16 ----------------
__global__ __launch_bounds__(256) void ln_bf16_kernel(const float* __restrict__ x,
                                                      const float* __restrict__ g,
                                                      const float* __restrict__ be,
                                                      short* __restrict__ out) {
    int row = blockIdx.x * 4 + (threadIdx.x >> 6);
    int lane = threadIdx.x & 63;
    const float* xp = x + (size_t)row * DIM;
    float v[6];
    float sum = 0.f, sumsq = 0.f;
#pragma unroll
    for (int j = 0; j < 6; j++) {
        float val = xp[lane + j * 64];
        v[j] = val; sum += val; sumsq += val * val;
    }
#pragma unroll
    for (int off = 1; off < 64; off <<= 1) {
        sum += __shfl_xor(sum, off, 64);
        sumsq += __shfl_xor(sumsq, off, 64);
    }
    float mean = sum * (1.f / DIM);
    float var = sumsq * (1.f / DIM) - mean * mean;
    float rstd = rsqrtf(var + 1e-5f);
    short* op = out + (size_t)row * DIM;
#pragma unroll
    for (int j = 0; j < 6; j++) {
        int c = lane + j * 64;
        op[c] = f2bf((v[j] - mean) * rstd * g[c] + be[c]);
    }
}

// ---------------- fused head: weight transposes + bias concat + LN1 + pos-MLP ----------
__global__ __launch_bounds__(256) void head_kernel(const float* __restrict__ Wq,
                                                   const float* __restrict__ Wk,
                                                   const float* __restrict__ Wv,
                                                   const float* __restrict__ Wo,
                                                   const float* __restrict__ mw1,
                                                   const float* __restrict__ mw2,
                                                   const float* __restrict__ bq,
                                                   const float* __restrict__ bk,
                                                   const float* __restrict__ bv,
                                                   const float* __restrict__ x,
                                                   const float* __restrict__ g1,
                                                   const float* __restrict__ be1,
                                                   const float* __restrict__ pos,
                                                   const float* __restrict__ pw1,
                                                   const float* __restrict__ pb1,
                                                   const float* __restrict__ pw2,
                                                   const float* __restrict__ pb2,
                                                   short* __restrict__ Wqkv_t,
                                                   short* __restrict__ Wo_t,
                                                   short* __restrict__ mw1_t,
                                                   short* __restrict__ mw2_t,
                                                   float* __restrict__ bqkv,
                                                   short* __restrict__ h_bf,
                                                   float* __restrict__ pe) {
    __shared__ float tile[32][33];
    __shared__ float pw2s[HD * HD];
    __shared__ float hsh[4][HD];
    const int id = blockIdx.x;
    const int t = threadIdx.x;
    if (id < 1728) {
        const float* src; short* dst; int K, N, tid;
        if (id < 144)       { src = Wq;  dst = Wqkv_t;          K = 384;  N = 384;  tid = id; }
        else if (id < 288)  { src = Wk;  dst = Wqkv_t + 147456; K = 384;  N = 384;  tid = id - 144; }
        else if (id < 432)  { src = Wv;  dst = Wqkv_t + 294912; K = 384;  N = 384;  tid = id - 288; }
        else if (id < 576)  { src = Wo;  dst = Wo_t;            K = 384;  N = 384;  tid = id - 432; }
        else if (id < 1152) { src = mw1; dst = mw1_t;           K = 384;  N = 1536; tid = id - 576; }
        else                { src = mw2; dst = mw2_t;           K = 1536; N = 384;  tid = id - 1152; }
        int ntx = N / 32;
        int n0 = (tid % ntx) * 32, k0 = (tid / ntx) * 32;
        int c = t & 31, r4 = t >> 5;
#pragma unroll
        for (int i = 0; i < 4; i++) {
            int r = r4 + i * 8;
            tile[r][c] = src[(size_t)(k0 + r) * N + n0 + c];
        }
        __syncthreads();
#pragma unroll
        for (int i = 0; i < 4; i++) {
            int r = r4 + i * 8;
            dst[(size_t)(n0 + r) * K + k0 + c] = f2bf(tile[c][r]);
        }
    } else if (id == 1728) {
        for (int i = t; i < 3 * DIM; i += 256)
            bqkv[i] = i < DIM ? bq[i] : (i < 2 * DIM ? bk[i - DIM] : bv[i - 2 * DIM]);
    } else if (id < 3777) {
        int row = (id - 1729) * 4 + (t >> 6);
        int lane = t & 63;
        const float* xp = x + (size_t)row * DIM;
        float v[6];
        float sum = 0.f, sumsq = 0.f;
#pragma unroll
        for (int j = 0; j < 6; j++) {
            float val = xp[lane + j * 64];
            v[j] = val; sum += val; sumsq += val * val;
        }
#pragma unroll
        for (int off = 1; off < 64; off <<= 1) {
            sum += __shfl_xor(sum, off, 64);
            sumsq += __shfl_xor(sumsq, off, 64);
        }
        float mean = sum * (1.f / DIM);
        float var = sumsq * (1.f / DIM) - mean * mean;
        float rstd = rsqrtf(var + 1e-5f);
        short* op = h_bf + (size_t)row * DIM;
#pragma unroll
        for (int j = 0; j < 6; j++) {
            int c = lane + j * 64;
            op[c] = f2bf((v[j] - mean) * rstd * g1[c] + be1[c]);
        }
    } else {
        int w = t >> 6, lane = t & 63;
        int p = (id - 3777) * 4 + w;
        for (int i = t; i < HD * HD; i += 256) pw2s[i] = pw2[i];
        float px = pos[(size_t)p * 3 + 0];
        float py = pos[(size_t)p * 3 + 1];
        float pz = pos[(size_t)p * 3 + 2];
        __syncthreads();
        if (lane < HD) {
            float hv = px * pw1[0 * HD + lane] + py * pw1[1 * HD + lane] + pz * pw1[2 * HD + lane] + pb1[lane];
            hsh[w][lane] = gelu_exact(hv);
        }
        if (lane < HD) {
            float o = pb2[lane];
#pragma unroll 8
            for (int i = 0; i < HD; i++) o += hsh[w][i] * pw2s[i * HD + lane];
            pe[(size_t)p * HD + lane] = o;
        }
    }
}

// ---------------- bf16 MFMA GEMM v5: 64x64 blocks ----------------
// C[M,N] = A[M,K] @ Bt[N,K]^T + bias. 64x64 tile, BK=64, 4 waves in 2x2 (each wave
// 32x32 = 2x2 MFMA tiles, acc 16 VGPR, LDS 16 KB): lightweight blocks -> 2-6x grid
// vs 128-tiles, keeps all 256 CUs fed on the N=384 GEMMs (Wo/MLP2 768 blocks).
// XOR-8 swizzle + 1-tile register prefetch. Pure-DS two-barrier staging.
// MODE 0: QKV fused -> q/k row-major bf16 (pe added to k), V^T permuted (key_new =
//         4*(key%16)+key/16 per 64-key tile, matching attention's packed-P layout).
// MODE 1: exact gelu -> bf16 (MLP1)
// MODE 2: of = res + (mask ? v : 0)  fp32 (Wo + residual)
// MODE 3: of = mask ? (res + v) : 0  fp32 (MLP2 + residual + mask)
template <int MODE>
__global__ __launch_bounds__(256) void gemm5_kernel(const short* __restrict__ A,
                                                    const short* __restrict__ Bt,
                                                    const float* __restrict__ bias,
                                                    const float* __restrict__ pe,
                                                    const float* __restrict__ res,
                                                    const int* __restrict__ mask,
                                                    float* __restrict__ of,
                                                    short* __restrict__ o0,
                                                    short* __restrict__ o1,
                                                    short* __restrict__ o2,
                                                    int M, int N, int K) {
    __shared__ short As[64 * 64];
    __shared__ short Bs[64 * 64];
    const int t = threadIdx.x, lane = t & 63, w = t >> 6;
    const int l16 = lane & 15, quad = lane >> 4;
    const int m0 = blockIdx.y * 64, n0 = blockIdx.x * 64;
    const int wm = (w & 1) * 32, wn = (w >> 1) * 32;

    // staging: 512 chunks per matrix, 2 per thread each
    const int rr = t >> 3, gc = t & 7, cshort = gc * 8;
    const short* gA[2]; const short* gB[2]; int ldso[2];
#pragma unroll
    for (int qc = 0; qc < 2; qc++) {
        int r = qc * 32 + rr;
        gA[qc] = A + (size_t)(m0 + r) * K + cshort;
        gB[qc] = Bt + (size_t)(n0 + r) * K + cshort;
        ldso[qc] = r * 64 + ((gc ^ (r & 7)) * 8);
    }

    floatx4 acc[2][2] = {};
    const int sA = l16 & 7;

    shortx8 ra[2], rb[2];
#pragma unroll
    for (int qc = 0; qc < 2; qc++) { ra[qc] = *(const shortx8*)gA[qc]; rb[qc] = *(const shortx8*)gB[qc]; }

    for (int k0 = 0; k0 < K; k0 += 64) {
        __syncthreads();
#pragma unroll
        for (int qc = 0; qc < 2; qc++) {
            *(shortx8*)&As[ldso[qc]] = ra[qc];
            *(shortx8*)&Bs[ldso[qc]] = rb[qc];
        }
        __syncthreads();
        if (k0 + 64 < K) {
#pragma unroll
            for (int qc = 0; qc < 2; qc++) {
                ra[qc] = *(const shortx8*)(gA[qc] + k0 + 64);
                rb[qc] = *(const shortx8*)(gB[qc] + k0 + 64);
            }
        }
#pragma unroll
        for (int kkc = 0; kkc < 2; kkc++) {
            shortx8 af[2], bfr[2];
            int slot = ((quad + kkc * 4) ^ sA) * 8;
#pragma unroll
            for (int i = 0; i < 2; i++) {
                af[i]  = *(const shortx8*)&As[(wm + i * 16 + l16) * 64 + slot];
                bfr[i] = *(const shortx8*)&Bs[(wn + i * 16 + l16) * 64 + slot];
            }
#pragma unroll
            for (int mi = 0; mi < 2; mi++)
#pragma unroll
                for (int ni = 0; ni < 2; ni++)
                    acc[mi][ni] = __builtin_amdgcn_mfma_f32_16x16x32_bf16(af[mi], bfr[ni], acc[mi][ni], 0, 0, 0);
        }
    }

    // epilogue: C row = m0+wm+mi*16+quad*4+reg, col = n0+wn+ni*16+l16
    const int seg = (MODE == 0) ? (n0 / DIM) : 0;
#pragma unroll
    for (int mi = 0; mi < 2; mi++) {
        int mrow0 = m0 + wm + mi * 16 + quad * 4;
        int4 mk4 = {0, 0, 0, 0};
        if (MODE == 2 || MODE == 3) mk4 = *(const int4*)&mask[mrow0];
#pragma unroll
        for (int ni = 0; ni < 2; ni++) {
            int n = n0 + wn + ni * 16 + l16;
            float bv = bias[n];
            float vals[4];
#pragma unroll
            for (int reg = 0; reg < 4; reg++) vals[reg] = acc[mi][ni][reg] + bv;
            if (MODE == 0) {
                int nl = n - seg * DIM;
                if (seg == 2) {
                    // V^T [b,h,d,T*64+key_new], key_new = 4*(key%16)+key/16
                    int hh = nl / HD, d = nl - hh * HD;
                    int bb = mrow0 / NN, nb = mrow0 - bb * NN;
                    int T = nb >> 6, ko = nb & 63;
                    int c16 = ko & 15, kb = ko >> 4;
                    short* vp = o2 + ((size_t)((bb * HEADS + hh) * HD + d)) * NN + T * 64 + kb;
#pragma unroll
                    for (int reg = 0; reg < 4; reg++) vp[4 * (c16 + reg)] = f2bf(vals[reg]);
                } else {
                    short* dstq = (seg == 0) ? o0 : o1;
                    int pc = nl % HD;
#pragma unroll
                    for (int reg = 0; reg < 4; reg++) {
                        int m = mrow0 + reg;
                        float val = vals[reg];
                        if (seg == 1) val += pe[(size_t)m * HD + pc];
                        dstq[(size_t)m * DIM + nl] = f2bf(val);
                    }
                }
            } else if (MODE == 1) {
#pragma unroll
                for (int reg = 0; reg < 4; reg++)
                    o0[(size_t)(mrow0 + reg) * N + n] = f2bf(gelu_exact(vals[reg]));
            } else if (MODE == 2) {
#pragma unroll
                for (int reg = 0; reg < 4; reg++) {
                    int m = mrow0 + reg;
                    int mk = ((const int*)&mk4)[reg];
                    of[(size_t)m * N + n] = res[(size_t)m * N + n] + (mk ? vals[reg] : 0.f);
                }
            } else {
#pragma unroll
                for (int reg = 0; reg < 4; reg++) {
                    int m = mrow0 + reg;
                    int mk = ((const int*)&mk4)[reg];
                    of[(size_t)m * N + n] = mk ? (res[(size_t)m * N + n] + vals[reg]) : 0.f;
                }
            }
        }
    }
}

// ---------------- MFMA flash attention v7: single-barrier double-buffered ----------------
__global__ __launch_bounds__(256) void attn7_kernel(const short* __restrict__ q,
                                                    const short* __restrict__ k,
                                                    const short* __restrict__ vt,
                                                    const int* __restrict__ mask,
                                                    short* __restrict__ out) {
    const int b = blockIdx.z, h = blockIdx.y;
    const int q0 = blockIdx.x * 128;
    const int t = threadIdx.x;
    const int lane = t & 63;
    const int w = t >> 6;
    const int l16 = lane & 15;
    const int quad = lane >> 4;

    __shared__ __align__(16) short SH[23552];
    __shared__ float madd2[2][64];

    {
        int buf = t >> 7, r = (t >> 1) & 63, zc = 6 + (t & 1);
        shortx8 z = {0, 0, 0, 0, 0, 0, 0, 0};
        *(shortx8*)&SH[buf * 4096 + r * 64 + ((zc ^ (r & 7)) * 8)] = z;
    }

    const size_t vtbase = (size_t)((b * HEADS + h) * HD) * NN;
    const short* gsrc[3]; int loff[3]; int gstep[3]; int bstr[3];
#pragma unroll
    for (int i = 0; i < 3; i++) {
        int u = t + i * 256;
        if (u < 384) {
            int r = u / 6, c = u - r * 6;
            gsrc[i] = k + ((size_t)(b * NN + r)) * DIM + h * HD + c * 8;
            gstep[i] = 64 * DIM;
            loff[i] = r * 64 + ((c ^ (r & 7)) * 8);
            bstr[i] = 4096;
        } else {
            int uu = u - 384;
            int d = uu >> 3, ck = uu & 7;
            gsrc[i] = vt + vtbase + (size_t)d * NN + ck * 8;
            gstep[i] = 64;
            loff[i] = 8192 + d * 64 + ((ck ^ (d & 7)) * 8);
            bstr[i] = 3072;
        }
    }

    shortx8 pre[3];
#pragma unroll
    for (int i = 0; i < 3; i++) pre[i] = *(const shortx8*)gsrc[i];
#pragma unroll
    for (int i = 0; i < 3; i++) *(shortx8*)&SH[loff[i]] = pre[i];
    if (t < 64) madd2[0][t] = mask[b * NN + t] ? 0.f : -1e30f;
#pragma unroll
    for (int i = 0; i < 3; i++) { gsrc[i] += gstep[i]; pre[i] = *(const shortx8*)gsrc[i]; }
    int mreg = (t < 64) ? mask[b * NN + 64 + t] : 0;

    shortx8 qf[2][2];
#pragma unroll
    for (int mt = 0; mt < 2; mt++) {
        const short* qp = q + ((size_t)(b * NN + q0 + w * 32 + mt * 16 + l16)) * DIM + h * HD;
        qf[mt][0] = *(const shortx8*)&qp[quad * 8];
        if (quad < 2) qf[mt][1] = *(const shortx8*)&qp[32 + quad * 8];
        else          qf[mt][1] = (shortx8){0, 0, 0, 0, 0, 0, 0, 0};
    }

    floatx4 acc[2][3] = {};
    float lsum[2][4] = {};
    const float cs = 0.14433756729740643f;
    const int plb = 14336 + w * 2304;
    const int sw = (l16 & 7);

    __syncthreads();

    for (int kt = 0; kt < 32; kt++) {
        const int cur = kt & 1, nxt = cur ^ 1;
        const int kso = cur * 4096, vto = 8192 + cur * 3072;

        shortx8 kb[4][2];
#pragma unroll
        for (int nt = 0; nt < 4; nt++) {
            int r = nt * 16 + l16;
            kb[nt][0] = *(const shortx8*)&SH[kso + r * 64 + ((quad ^ sw) * 8)];
            kb[nt][1] = *(const shortx8*)&SH[kso + r * 64 + (((4 + quad) ^ sw) * 8)];
        }
        if (kt < 31) {
#pragma unroll
            for (int i = 0; i < 3; i++) *(shortx8*)&SH[loff[i] + nxt * bstr[i]] = pre[i];
            if (t < 64) madd2[nxt][t] = mreg ? 0.f : -1e30f;
            if (kt < 30) {
#pragma unroll
                for (int i = 0; i < 3; i++) { gsrc[i] += gstep[i]; pre[i] = *(const shortx8*)gsrc[i]; }
                if (t < 64) mreg = mask[b * NN + (kt + 2) * 64 + t];
            }
        }

        floatx4 S[2][4];
#pragma unroll
        for (int nt = 0; nt < 4; nt++)
#pragma unroll
            for (int mt = 0; mt < 2; mt++) {
                floatx4 s = {0.f, 0.f, 0.f, 0.f};
                s = __builtin_amdgcn_mfma_f32_16x16x32_bf16(qf[mt][0], kb[nt][0], s, 0, 0, 0);
                s = __builtin_amdgcn_mfma_f32_16x16x32_bf16(qf[mt][1], kb[nt][1], s, 0, 0, 0);
                S[mt][nt] = s;
            }
#pragma unroll
        for (int mt = 0; mt < 2; mt++) {
            float p[4][4];
#pragma unroll
            for (int nt = 0; nt < 4; nt++) {
                float ad = madd2[cur][nt * 16 + l16];
#pragma unroll
                for (int reg = 0; reg < 4; reg++) {
                    float pv = __expf(S[mt][nt][reg] * cs + ad);
                    p[nt][reg] = pv;
                    lsum[mt][reg] += pv;
                }
            }
#pragma unroll
            for (int reg = 0; reg < 4; reg++) {
                *(uint2*)&SH[plb + (mt * 16 + quad * 4 + reg) * 72 + l16 * 4] =
                    make_uint2(pkbf(p[0][reg], p[1][reg]), pkbf(p[2][reg], p[3][reg]));
            }
        }
#pragma unroll
        for (int c = 0; c < 2; c++) {
            shortx8 pf[2];
#pragma unroll
            for (int mt = 0; mt < 2; mt++)
                pf[mt] = *(const shortx8*)&SH[plb + (mt * 16 + l16) * 72 + c * 32 + quad * 8];
#pragma unroll
            for (int dt = 0; dt < 3; dt++) {
                shortx8 vf = *(const shortx8*)&SH[vto + (dt * 16 + l16) * 64 + (((c * 4 + quad) ^ sw) * 8)];
#pragma unroll
                for (int mt = 0; mt < 2; mt++)
                    acc[mt][dt] = __builtin_amdgcn_mfma_f32_16x16x32_bf16(pf[mt], vf, acc[mt][dt], 0, 0, 0);
            }
        }
        __syncthreads();
    }

#pragma unroll
    for (int mt = 0; mt < 2; mt++)
#pragma unroll
        for (int reg = 0; reg < 4; reg++) {
            float s = lsum[mt][reg];
#pragma unroll
            for (int off = 1; off < 16; off <<= 1) s += __shfl_xor(s, off, 64);
            lsum[mt][reg] = 1.f / s;
        }
#pragma unroll
    for (int mt = 0; mt < 2; mt++)
#pragma unroll
        for (int dt = 0; dt < 3; dt++)
#pragma unroll
            for (int reg = 0; reg < 4; reg++) {
                size_t row = (size_t)(b * NN + q0 + w * 32 + mt * 16 + quad * 4 + reg);
                out[row * DIM + h * HD + dt * 16 + l16] = f2bf_c(acc[mt][dt][reg] * lsum[mt][reg]);
            }
}

extern "C" void kernel_launch(void* const* d_in, const int* in_sizes, int n_in,
                              void* d_out, int out_size, void* d_ws, size_t ws_size,
                              hipStream_t stream) {
    const float* x   = (const float*)d_in[0];
    const float* pos = (const float*)d_in[1];
    const int*   mask= (const int*)  d_in[2];
    const float* Wq  = (const float*)d_in[3];
    const float* bq  = (const float*)d_in[4];
    const float* Wk  = (const float*)d_in[5];
    const float* bk  = (const float*)d_in[6];
    const float* Wv  = (const float*)d_in[7];
    const float* bv  = (const float*)d_in[8];
    const float* pw1 = (const float*)d_in[9];
    const float* pb1 = (const float*)d_in[10];
    const float* pw2 = (const float*)d_in[11];
    const float* pb2 = (const float*)d_in[12];
    const float* Wo  = (const float*)d_in[13];
    const float* bo  = (const float*)d_in[14];
    const float* mw1 = (const float*)d_in[15];
    const float* mb1 = (const float*)d_in[16];
    const float* mw2 = (const float*)d_in[17];
    const float* mb2 = (const float*)d_in[18];
    const float* g1  = (const float*)d_in[19];
    const float* be1 = (const float*)d_in[20];
    const float* g2  = (const float*)d_in[21];
    const float* be2 = (const float*)d_in[22];
    float* out = (float*)d_out;

    // workspace layout (bytes)
    char* wsb = (char*)d_ws;
    short* h_bf    = (short*)(wsb + 0);           // 6291456
    short* q_bf    = (short*)(wsb + 6291456);
    short* k_bf    = (short*)(wsb + 12582912);
    short* vt_bf   = (short*)(wsb + 18874368);    // V^T [b][h][d][n], key-permuted
    short* attn_bf = (short*)(wsb + 25165824);
    short* mlph_bf = h_bf;                        // overlays h|q|k|vt (dead by MLP1)
    float* pebuf   = (float*)(wsb + 31457280);    // 1572864
    float* x1      = (float*)(wsb + 33030144);    // 12582912
    short* h2_bf   = (short*)(wsb + 45613056);    // 6291456
    short* Wqkv_t  = (short*)(wsb + 51904512);    // [1152][384] bf16
    short* Wo_t    = (short*)(wsb + 52789248);    // [384][384]
    short* mw1_t   = (short*)(wsb + 53084160);    // [1536][384]
    short* mw2_t   = (short*)(wsb + 54263808);    // [384][1536]
    float* bqkv    = (float*)(wsb + 55443456);    // [1152]

    // --- fused head: weight prep + LN1 + pos-MLP (1 launch) ---
    head_kernel<<<5825, 256, 0, stream>>>(Wq, Wk, Wv, Wo, mw1, mw2, bq, bk, bv,
                                          x, g1, be1, pos, pw1, pb1, pw2, pb2,
                                          Wqkv_t, Wo_t, mw1_t, mw2_t, bqkv, h_bf, pebuf);

    // fused QKV: 64x64 blocks -> 2304 blocks (9/CU)
    gemm5_kernel<0><<<dim3(3 * DIM / 64, ROWS / 64), 256, 0, stream>>>(
        h_bf, Wqkv_t, bqkv, pebuf, nullptr, nullptr, nullptr, q_bf, k_bf, vt_bf,
        ROWS, 3 * DIM, DIM);

    // attention: 512 blocks of 128 queries, single-barrier dbuf pipeline
    attn7_kernel<<<dim3(NN / 128, HEADS, BB), 256, 0, stream>>>(
        q_bf, k_bf, vt_bf, mask, attn_bf);

    // Wo + residual + mask -> x1 fp32 (768 blocks, 3/CU)
    gemm5_kernel<2><<<dim3(DIM / 64, ROWS / 64), 256, 0, stream>>>(
        attn_bf, Wo_t, bo, nullptr, x, mask, x1, nullptr, nullptr, nullptr,
        ROWS, DIM, DIM);

    ln_bf16_kernel<<<ROWS / 4, 256, 0, stream>>>(x1, g2, be2, h2_bf);

    // MLP1 (exact gelu) -> bf16 hidden (3072 blocks)
    gemm5_kernel<1><<<dim3(MLPH / 64, ROWS / 64), 256, 0, stream>>>(
        h2_bf, mw1_t, mb1, nullptr, nullptr, nullptr, nullptr, mlph_bf, nullptr, nullptr,
        ROWS, MLPH, DIM);

    // MLP2 + residual + mask -> out fp32 (768 blocks)
    gemm5_kernel<3><<<dim3(DIM / 64, ROWS / 64), 256, 0, stream>>>(
        mlph_bf, mw2_t, mb2, nullptr, x1, mask, out, nullptr, nullptr, nullptr,
        ROWS, DIM, MLPH);
}